// Round 1
// baseline (5687.785 us; speedup 1.0000x reference)
//
#include <hip/hip_runtime.h>
#include <hip/hip_bf16.h>
#include <math.h>

#define N_NODES 20000
#define N_EDGES 320000
#define IN_CH   128
#define HEADS   8
#define CPH     128
#define HCH     1024
#define NG      64
#define ETOT    (N_EDGES + N_NODES)

// ---- order-preserving float <-> uint for atomicMax on signed floats ----
__device__ __forceinline__ unsigned enc_f(float f) {
    unsigned u = __float_as_uint(f);
    return (u & 0x80000000u) ? ~u : (u | 0x80000000u);
}
__device__ __forceinline__ float dec_f(unsigned u) {
    return (u & 0x80000000u) ? __uint_as_float(u ^ 0x80000000u)
                             : __uint_as_float(~u);
}

// ---- init: m = enc(-inf), denom = 0, pooled = 0, cnt = 0 ----
__global__ void init_kernel(unsigned* __restrict__ m, float* __restrict__ denom,
                            float* __restrict__ pooled, float* __restrict__ cnt) {
    int i = blockIdx.x * blockDim.x + threadIdx.x;
    const int nm = N_NODES * HEADS;
    if (i < nm) { m[i] = 0x007FFFFFu; denom[i] = 0.0f; }   // enc(-inf)
    if (i < NG * CPH) pooled[i] = 0.0f;
    if (i < NG) cnt[i] = 0.0f;
}

// ---- C[m][n] = act( sum_k A[m][k]*W[n][k] + bias[n] ), W row-major [NN][K] ----
// tiles 64x64, block 256 (16x16), each thread 4x4. K must be multiple of 128.
__global__ __launch_bounds__(256) void gemm_nt(
    const float* __restrict__ A, const float* __restrict__ W,
    const float* __restrict__ bias, float* __restrict__ C,
    int M, int NN, int K, int act)
{
    __shared__ float xs[128][68];   // [k][row], stride 68 floats = 272B (16B aligned)
    __shared__ float ws[128][68];
    const int t  = threadIdx.x;
    const int tx = t & 15, ty = t >> 4;
    const int row0 = blockIdx.x * 64;
    const int col0 = blockIdx.y * 64;

    float acc[4][4] = {};

    for (int k0 = 0; k0 < K; k0 += 128) {
        #pragma unroll
        for (int it = 0; it < 8; ++it) {
            int flat = (t + it * 256) * 4;      // 0..8191 within 64x128 tile
            int r = flat >> 7;
            int k = flat & 127;
            int gr = row0 + r; if (gr >= M) gr = M - 1;
            float4 v  = *(const float4*)&A[(size_t)gr * K + k0 + k];
            xs[k + 0][r] = v.x; xs[k + 1][r] = v.y;
            xs[k + 2][r] = v.z; xs[k + 3][r] = v.w;
            float4 wv = *(const float4*)&W[(size_t)(col0 + r) * K + k0 + k];
            ws[k + 0][r] = wv.x; ws[k + 1][r] = wv.y;
            ws[k + 2][r] = wv.z; ws[k + 3][r] = wv.w;
        }
        __syncthreads();
        #pragma unroll 4
        for (int k = 0; k < 128; ++k) {
            float4 a4 = *(const float4*)&xs[k][ty * 4];
            float4 b4 = *(const float4*)&ws[k][tx * 4];
            float av[4] = {a4.x, a4.y, a4.z, a4.w};
            float bv[4] = {b4.x, b4.y, b4.z, b4.w};
            #pragma unroll
            for (int i = 0; i < 4; ++i)
                #pragma unroll
                for (int j = 0; j < 4; ++j)
                    acc[i][j] += av[i] * bv[j];
        }
        __syncthreads();
    }

    #pragma unroll
    for (int i = 0; i < 4; ++i) {
        int r = row0 + ty * 4 + i;
        if (r >= M) continue;
        #pragma unroll
        for (int j = 0; j < 4; ++j) {
            int c = col0 + tx * 4 + j;
            float v = acc[i][j] + bias[c];
            if (act == 1) v = v > 0.0f ? v : expm1f(v);   // ELU
            C[(size_t)r * NN + c] = v;
        }
    }
}

// ---- per-edge attention logits + running segment max ----
__global__ __launch_bounds__(256) void edge_logits_kernel(
    const float* __restrict__ xl, const float* __restrict__ xr,
    const int* __restrict__ ei, const float* __restrict__ att,
    float* __restrict__ logits, unsigned* __restrict__ mbuf)
{
    const int e = blockIdx.x;
    int src, dst;
    if (e < N_EDGES) { src = ei[e]; dst = ei[N_EDGES + e]; }
    else             { src = dst = e - N_EDGES; }
    const int t = threadIdx.x;

    const float4 a = *(const float4*)&xl[(size_t)src * HCH + t * 4];
    const float4 b = *(const float4*)&xr[(size_t)dst * HCH + t * 4];
    const float4 w = *(const float4*)&att[t * 4];

    float v0 = a.x + b.x; v0 = v0 > 0.0f ? v0 : 0.2f * v0;
    float v1 = a.y + b.y; v1 = v1 > 0.0f ? v1 : 0.2f * v1;
    float v2 = a.z + b.z; v2 = v2 > 0.0f ? v2 : 0.2f * v2;
    float v3 = a.w + b.w; v3 = v3 > 0.0f ? v3 : 0.2f * v3;
    float p = v0 * w.x + v1 * w.y + v2 * w.z + v3 * w.w;

    #pragma unroll
    for (int off = 16; off; off >>= 1) p += __shfl_down(p, off, 32);

    if ((t & 31) == 0) {
        int h = t >> 5;
        logits[(size_t)e * HEADS + h] = p;
        atomicMax(&mbuf[dst * HEADS + h], enc_f(p));
    }
}

// ---- a = exp(logit - m[dst]); denom[dst] += a  (in-place over logits) ----
__global__ void edge_exp_kernel(float* __restrict__ logits,
                                const unsigned* __restrict__ mbuf,
                                float* __restrict__ denom,
                                const int* __restrict__ ei)
{
    const int tot = ETOT * HEADS;
    for (int i = blockIdx.x * blockDim.x + threadIdx.x; i < tot;
         i += gridDim.x * blockDim.x) {
        int e = i >> 3, h = i & 7;
        int dst = (e < N_EDGES) ? ei[N_EDGES + e] : (e - N_EDGES);
        float a = __expf(logits[i] - dec_f(mbuf[dst * HEADS + h]));
        logits[i] = a;
        atomicAdd(&denom[dst * HEADS + h], a);
    }
}

// ---- out[dst] += alpha * x_l[src] ----
__global__ __launch_bounds__(256) void edge_agg_kernel(
    const float* __restrict__ xl, const float* __restrict__ a,
    const float* __restrict__ denom, const int* __restrict__ ei,
    float* __restrict__ outc)
{
    const int e = blockIdx.x;
    int src, dst;
    if (e < N_EDGES) { src = ei[e]; dst = ei[N_EDGES + e]; }
    else             { src = dst = e - N_EDGES; }
    const int t = threadIdx.x;
    const int h = t >> 5;

    float alpha = a[(size_t)e * HEADS + h] / (denom[dst * HEADS + h] + 1e-16f);
    const float4 v = *(const float4*)&xl[(size_t)src * HCH + t * 4];
    float* o = &outc[(size_t)dst * HCH + t * 4];
    atomicAdd(o + 0, alpha * v.x);
    atomicAdd(o + 1, alpha * v.y);
    atomicAdd(o + 2, alpha * v.z);
    atomicAdd(o + 3, alpha * v.w);
}

// ---- mean-pool accumulation ----
__global__ __launch_bounds__(128) void pool_kernel(
    const float* __restrict__ h, const int* __restrict__ batch,
    float* __restrict__ pooled, float* __restrict__ cnt)
{
    const int n = blockIdx.x;
    const int t = threadIdx.x;
    const int g = batch[n];
    atomicAdd(&pooled[g * CPH + t], h[(size_t)n * CPH + t]);
    if (t == 0) atomicAdd(&cnt[g], 1.0f);
}

// ---- MLP head: one thread per graph ----
__global__ __launch_bounds__(64) void head_kernel(
    const float* __restrict__ pooled, const float* __restrict__ cnt,
    const float* __restrict__ W1, const float* __restrict__ b1,
    const float* __restrict__ W2, const float* __restrict__ b2,
    const float* __restrict__ W3, const float* __restrict__ b3,
    float* __restrict__ out)
{
    const int g = threadIdx.x;
    const float inv = 1.0f / fmaxf(cnt[g], 1.0f);

    float y1[16];
    for (int j = 0; j < 16; ++j) {
        float s = 0.0f;
        for (int k = 0; k < CPH; ++k) s += W1[j * CPH + k] * pooled[g * CPH + k];
        s = s * inv + b1[j];
        y1[j] = fmaxf(s, 0.0f);
    }
    float y2[32];
    for (int j = 0; j < 32; ++j) {
        float s = b2[j];
        for (int k = 0; k < 16; ++k) s += W2[j * 16 + k] * y1[k];
        y2[j] = fmaxf(s, 0.0f);
    }
    for (int u = 0; u < 5; ++u) {
        float s = b3[u];
        for (int k = 0; k < 32; ++k) s += W3[u * 32 + k] * y2[k];
        out[g * 5 + u] = s;
    }
}

extern "C" void kernel_launch(void* const* d_in, const int* in_sizes, int n_in,
                              void* d_out, int out_size, void* d_ws, size_t ws_size,
                              hipStream_t stream)
{
    const float* x         = (const float*)d_in[0];
    const int*   ei        = (const int*)  d_in[1];
    const int*   batch     = (const int*)  d_in[2];
    const float* Wl        = (const float*)d_in[3];
    const float* bl        = (const float*)d_in[4];
    const float* Wr        = (const float*)d_in[5];
    const float* br        = (const float*)d_in[6];
    const float* att       = (const float*)d_in[7];
    const float* Wres      = (const float*)d_in[8];
    const float* bias_conv = (const float*)d_in[9];
    const float* Wlin      = (const float*)d_in[10];
    const float* blin      = (const float*)d_in[11];
    const float* W1        = (const float*)d_in[12];
    const float* b1        = (const float*)d_in[13];
    const float* W2        = (const float*)d_in[14];
    const float* b2        = (const float*)d_in[15];
    const float* W3        = (const float*)d_in[16];
    const float* b3        = (const float*)d_in[17];
    float* out = (float*)d_out;

    // workspace layout (floats)
    float*    xl     = (float*)d_ws;                          // N*HC
    float*    xr     = xl + (size_t)N_NODES * HCH;            // N*HC
    float*    outc   = xr + (size_t)N_NODES * HCH;            // N*HC
    float*    logits = outc + (size_t)N_NODES * HCH;          // ETOT*H (reused as 'a')
    unsigned* mbuf   = (unsigned*)(logits + (size_t)ETOT * HEADS);  // N*H
    float*    denom  = (float*)(mbuf + (size_t)N_NODES * HEADS);    // N*H
    float*    hbuf   = denom + (size_t)N_NODES * HEADS;       // N*CPH
    float*    pooled = hbuf + (size_t)N_NODES * CPH;          // NG*CPH
    float*    cnt    = pooled + (size_t)NG * CPH;             // NG

    init_kernel<<<(N_NODES * HEADS + 255) / 256, 256, 0, stream>>>(mbuf, denom, pooled, cnt);

    dim3 g1((N_NODES + 63) / 64, HCH / 64);
    gemm_nt<<<g1, 256, 0, stream>>>(x, Wl,   bl,        xl,   N_NODES, HCH, IN_CH, 0);
    gemm_nt<<<g1, 256, 0, stream>>>(x, Wr,   br,        xr,   N_NODES, HCH, IN_CH, 0);
    gemm_nt<<<g1, 256, 0, stream>>>(x, Wres, bias_conv, outc, N_NODES, HCH, IN_CH, 0);

    edge_logits_kernel<<<ETOT, 256, 0, stream>>>(xl, xr, ei, att, logits, mbuf);
    edge_exp_kernel<<<2048, 256, 0, stream>>>(logits, mbuf, denom, ei);
    edge_agg_kernel<<<ETOT, 256, 0, stream>>>(xl, logits, denom, ei, outc);

    dim3 g5((N_NODES + 63) / 64, CPH / 64);
    gemm_nt<<<g5, 256, 0, stream>>>(outc, Wlin, blin, hbuf, N_NODES, CPH, HCH, 1);

    pool_kernel<<<N_NODES, 128, 0, stream>>>(hbuf, batch, pooled, cnt);

    head_kernel<<<1, 64, 0, stream>>>(pooled, cnt, W1, b1, W2, b2, W3, b3, out);
}

// Round 2
// 1546.108 us; speedup vs baseline: 3.6788x; 3.6788x over previous
//
#include <hip/hip_runtime.h>
#include <hip/hip_bf16.h>
#include <math.h>

#define N_NODES 20000
#define N_EDGES 320000
#define IN_CH   128
#define HEADS   8
#define CPH     128
#define HCH     1024
#define NG      64
#define ETOT    (N_EDGES + N_NODES)

// ---- init: deg = 0, pooled = 0, cnt = 0 ----
__global__ void init_kernel(int* __restrict__ deg, float* __restrict__ pooled,
                            float* __restrict__ cnt) {
    int i = blockIdx.x * blockDim.x + threadIdx.x;
    if (i < N_NODES) deg[i] = 0;
    if (i < NG * CPH) pooled[i] = 0.0f;
    if (i < NG) cnt[i] = 0.0f;
}

// ---- C[m][n] = act( sum_k A[m][k]*W[n][k] + bias[n] ), W row-major [NN][K] ----
__global__ __launch_bounds__(256) void gemm_nt(
    const float* __restrict__ A, const float* __restrict__ W,
    const float* __restrict__ bias, float* __restrict__ C,
    int M, int NN, int K, int act)
{
    __shared__ float xs[128][68];
    __shared__ float ws[128][68];
    const int t  = threadIdx.x;
    const int tx = t & 15, ty = t >> 4;
    const int row0 = blockIdx.x * 64;
    const int col0 = blockIdx.y * 64;

    float acc[4][4] = {};

    for (int k0 = 0; k0 < K; k0 += 128) {
        #pragma unroll
        for (int it = 0; it < 8; ++it) {
            int flat = (t + it * 256) * 4;
            int r = flat >> 7;
            int k = flat & 127;
            int gr = row0 + r; if (gr >= M) gr = M - 1;
            float4 v  = *(const float4*)&A[(size_t)gr * K + k0 + k];
            xs[k + 0][r] = v.x; xs[k + 1][r] = v.y;
            xs[k + 2][r] = v.z; xs[k + 3][r] = v.w;
            float4 wv = *(const float4*)&W[(size_t)(col0 + r) * K + k0 + k];
            ws[k + 0][r] = wv.x; ws[k + 1][r] = wv.y;
            ws[k + 2][r] = wv.z; ws[k + 3][r] = wv.w;
        }
        __syncthreads();
        #pragma unroll 4
        for (int k = 0; k < 128; ++k) {
            float4 a4 = *(const float4*)&xs[k][ty * 4];
            float4 b4 = *(const float4*)&ws[k][tx * 4];
            float av[4] = {a4.x, a4.y, a4.z, a4.w};
            float bv[4] = {b4.x, b4.y, b4.z, b4.w};
            #pragma unroll
            for (int i = 0; i < 4; ++i)
                #pragma unroll
                for (int j = 0; j < 4; ++j)
                    acc[i][j] += av[i] * bv[j];
        }
        __syncthreads();
    }

    #pragma unroll
    for (int i = 0; i < 4; ++i) {
        int r = row0 + ty * 4 + i;
        if (r >= M) continue;
        #pragma unroll
        for (int j = 0; j < 4; ++j) {
            int c = col0 + tx * 4 + j;
            float v = acc[i][j] + bias[c];
            if (act == 1) v = v > 0.0f ? v : expm1f(v);   // ELU
            C[(size_t)r * NN + c] = v;
        }
    }
}

// ---- per-edge attention logits (raw; softmax handled in agg) ----
__global__ __launch_bounds__(256) void edge_logits_kernel(
    const float* __restrict__ xl, const float* __restrict__ xr,
    const int* __restrict__ ei, const float* __restrict__ att,
    float* __restrict__ logits)
{
    const int e = blockIdx.x;
    int src, dst;
    if (e < N_EDGES) { src = ei[e]; dst = ei[N_EDGES + e]; }
    else             { src = dst = e - N_EDGES; }
    const int t = threadIdx.x;

    const float4 a = *(const float4*)&xl[(size_t)src * HCH + t * 4];
    const float4 b = *(const float4*)&xr[(size_t)dst * HCH + t * 4];
    const float4 w = *(const float4*)&att[t * 4];

    float v0 = a.x + b.x; v0 = v0 > 0.0f ? v0 : 0.2f * v0;
    float v1 = a.y + b.y; v1 = v1 > 0.0f ? v1 : 0.2f * v1;
    float v2 = a.z + b.z; v2 = v2 > 0.0f ? v2 : 0.2f * v2;
    float v3 = a.w + b.w; v3 = v3 > 0.0f ? v3 : 0.2f * v3;
    float p = v0 * w.x + v1 * w.y + v2 * w.z + v3 * w.w;

    #pragma unroll
    for (int off = 16; off; off >>= 1) p += __shfl_down(p, off, 32);

    if ((t & 31) == 0) logits[(size_t)e * HEADS + (t >> 5)] = p;
}

// ---- CSR build: histogram ----
__global__ void hist_kernel(const int* __restrict__ ei, int* __restrict__ deg) {
    for (int e = blockIdx.x * blockDim.x + threadIdx.x; e < ETOT;
         e += gridDim.x * blockDim.x) {
        int dst = (e < N_EDGES) ? ei[N_EDGES + e] : (e - N_EDGES);
        atomicAdd(&deg[dst], 1);
    }
}

// ---- CSR build: single-block exclusive scan -> rowptr, wof ----
__global__ __launch_bounds__(256) void scan_kernel(
    const int* __restrict__ deg, int* __restrict__ rowptr, int* __restrict__ wof)
{
    __shared__ int sbuf[256];
    __shared__ int carry;
    const int t = threadIdx.x;
    if (t == 0) { carry = 0; rowptr[0] = 0; }
    __syncthreads();
    for (int base = 0; base < N_NODES; base += 256) {
        int i = base + t;
        int orig = (i < N_NODES) ? deg[i] : 0;
        sbuf[t] = orig;
        __syncthreads();
        #pragma unroll
        for (int off = 1; off < 256; off <<= 1) {
            int add = (t >= off) ? sbuf[t - off] : 0;
            __syncthreads();
            sbuf[t] += add;
            __syncthreads();
        }
        int inc = sbuf[t] + carry;
        if (i < N_NODES) { rowptr[i + 1] = inc; wof[i] = inc - orig; }
        __syncthreads();
        if (t == 255) carry = inc;
        __syncthreads();
    }
}

// ---- CSR build: scatter edge ids ----
__global__ void scatter_kernel(const int* __restrict__ ei, int* __restrict__ wof,
                               int* __restrict__ csr_src, int* __restrict__ csr_eid)
{
    for (int e = blockIdx.x * blockDim.x + threadIdx.x; e < ETOT;
         e += gridDim.x * blockDim.x) {
        int src, dst;
        if (e < N_EDGES) { src = ei[e]; dst = ei[N_EDGES + e]; }
        else             { src = dst = e - N_EDGES; }
        int p = atomicAdd(&wof[dst], 1);
        csr_src[p] = src;
        csr_eid[p] = e;
    }
}

// ---- fused segment softmax + weighted aggregation, one block per dst ----
__global__ __launch_bounds__(256) void agg_csr_kernel(
    const float* __restrict__ xl, const float* __restrict__ logits,
    const int* __restrict__ rowptr, const int* __restrict__ csr_src,
    const int* __restrict__ csr_eid, float* __restrict__ outc)
{
    const int dst = blockIdx.x;
    const int t = threadIdx.x;
    const int h = t >> 5;
    const int beg = rowptr[dst], end = rowptr[dst + 1];

    // pass 1: per-head max + denom (redundant across the 32 lanes of a head)
    float m = -INFINITY;
    for (int j = beg; j < end; ++j)
        m = fmaxf(m, logits[(size_t)csr_eid[j] * HEADS + h]);
    float s = 0.0f;
    for (int j = beg; j < end; ++j)
        s += __expf(logits[(size_t)csr_eid[j] * HEADS + h] - m);
    const float inv = 1.0f / (s + 1e-16f);

    // pass 2: weighted gather-accumulate
    float4 acc = {0.0f, 0.0f, 0.0f, 0.0f};
    for (int j = beg; j < end; ++j) {
        const int src = csr_src[j];
        const float w = __expf(logits[(size_t)csr_eid[j] * HEADS + h] - m) * inv;
        const float4 v = *(const float4*)&xl[(size_t)src * HCH + t * 4];
        acc.x += w * v.x; acc.y += w * v.y;
        acc.z += w * v.z; acc.w += w * v.w;
    }

    float4* o = (float4*)&outc[(size_t)dst * HCH + t * 4];
    float4 cur = *o;
    cur.x += acc.x; cur.y += acc.y; cur.z += acc.z; cur.w += acc.w;
    *o = cur;
}

// ---- mean-pool accumulation ----
__global__ __launch_bounds__(128) void pool_kernel(
    const float* __restrict__ h, const int* __restrict__ batch,
    float* __restrict__ pooled, float* __restrict__ cnt)
{
    const int n = blockIdx.x;
    const int t = threadIdx.x;
    const int g = batch[n];
    atomicAdd(&pooled[g * CPH + t], h[(size_t)n * CPH + t]);
    if (t == 0) atomicAdd(&cnt[g], 1.0f);
}

// ---- MLP head: one thread per graph ----
__global__ __launch_bounds__(64) void head_kernel(
    const float* __restrict__ pooled, const float* __restrict__ cnt,
    const float* __restrict__ W1, const float* __restrict__ b1,
    const float* __restrict__ W2, const float* __restrict__ b2,
    const float* __restrict__ W3, const float* __restrict__ b3,
    float* __restrict__ out)
{
    const int g = threadIdx.x;
    const float inv = 1.0f / fmaxf(cnt[g], 1.0f);

    float y1[16];
    for (int j = 0; j < 16; ++j) {
        float s = 0.0f;
        for (int k = 0; k < CPH; ++k) s += W1[j * CPH + k] * pooled[g * CPH + k];
        s = s * inv + b1[j];
        y1[j] = fmaxf(s, 0.0f);
    }
    float y2[32];
    for (int j = 0; j < 32; ++j) {
        float s = b2[j];
        for (int k = 0; k < 16; ++k) s += W2[j * 16 + k] * y1[k];
        y2[j] = fmaxf(s, 0.0f);
    }
    for (int u = 0; u < 5; ++u) {
        float s = b3[u];
        for (int k = 0; k < 32; ++k) s += W3[u * 32 + k] * y2[k];
        out[g * 5 + u] = s;
    }
}

extern "C" void kernel_launch(void* const* d_in, const int* in_sizes, int n_in,
                              void* d_out, int out_size, void* d_ws, size_t ws_size,
                              hipStream_t stream)
{
    const float* x         = (const float*)d_in[0];
    const int*   ei        = (const int*)  d_in[1];
    const int*   batch     = (const int*)  d_in[2];
    const float* Wl        = (const float*)d_in[3];
    const float* bl        = (const float*)d_in[4];
    const float* Wr        = (const float*)d_in[5];
    const float* br        = (const float*)d_in[6];
    const float* att       = (const float*)d_in[7];
    const float* Wres      = (const float*)d_in[8];
    const float* bias_conv = (const float*)d_in[9];
    const float* Wlin      = (const float*)d_in[10];
    const float* blin      = (const float*)d_in[11];
    const float* W1        = (const float*)d_in[12];
    const float* b1        = (const float*)d_in[13];
    const float* W2        = (const float*)d_in[14];
    const float* b2        = (const float*)d_in[15];
    const float* W3        = (const float*)d_in[16];
    const float* b3        = (const float*)d_in[17];
    float* out = (float*)d_out;

    // workspace layout (floats)
    float* xl     = (float*)d_ws;                     // N*HC       80 MB
    float* xr     = xl   + (size_t)N_NODES * HCH;     // N*HC       80 MB
    float* outc   = xr   + (size_t)N_NODES * HCH;     // N*HC       80 MB
    float* logits = outc + (size_t)N_NODES * HCH;     // ETOT*H     10.9 MB
    float* hbuf   = logits + (size_t)ETOT * HEADS;    // N*CPH      10.2 MB (CSR aliased below)
    float* pooled = hbuf + (size_t)N_NODES * CPH;     // NG*CPH
    float* cnt    = pooled + (size_t)NG * CPH;        // NG

    // CSR structures alias hbuf (used strictly before gemm writes hbuf)
    int* deg     = (int*)hbuf;                        // N
    int* rowptr  = deg + N_NODES;                     // N+1
    int* wof     = rowptr + N_NODES + 1;              // N
    int* csr_src = wof + N_NODES;                     // ETOT
    int* csr_eid = csr_src + ETOT;                    // ETOT   (total 2.96 MB < 10.2 MB)

    init_kernel<<<(N_NODES + 255) / 256, 256, 0, stream>>>(deg, pooled, cnt);

    dim3 g1((N_NODES + 63) / 64, HCH / 64);
    gemm_nt<<<g1, 256, 0, stream>>>(x, Wl,   bl,        xl,   N_NODES, HCH, IN_CH, 0);
    gemm_nt<<<g1, 256, 0, stream>>>(x, Wr,   br,        xr,   N_NODES, HCH, IN_CH, 0);
    gemm_nt<<<g1, 256, 0, stream>>>(x, Wres, bias_conv, outc, N_NODES, HCH, IN_CH, 0);

    edge_logits_kernel<<<ETOT, 256, 0, stream>>>(xl, xr, ei, att, logits);

    hist_kernel<<<1024, 256, 0, stream>>>(ei, deg);
    scan_kernel<<<1, 256, 0, stream>>>(deg, rowptr, wof);
    scatter_kernel<<<1024, 256, 0, stream>>>(ei, wof, csr_src, csr_eid);

    agg_csr_kernel<<<N_NODES, 256, 0, stream>>>(xl, logits, rowptr, csr_src, csr_eid, outc);

    dim3 g5((N_NODES + 63) / 64, CPH / 64);
    gemm_nt<<<g5, 256, 0, stream>>>(outc, Wlin, blin, hbuf, N_NODES, CPH, HCH, 1);

    pool_kernel<<<N_NODES, 128, 0, stream>>>(hbuf, batch, pooled, cnt);

    head_kernel<<<1, 64, 0, stream>>>(pooled, cnt, W1, b1, W2, b2, W3, b3, out);
}

// Round 3
// 830.603 us; speedup vs baseline: 6.8478x; 1.8614x over previous
//
#include <hip/hip_runtime.h>
#include <hip/hip_bf16.h>
#include <math.h>

#define N_NODES 20000
#define N_EDGES 320000
#define IN_CH   128
#define HEADS   8
#define CPH     128
#define HCH     1024
#define NG      64
#define ETOT    (N_EDGES + N_NODES)

typedef __attribute__((ext_vector_type(8))) short s8v;
typedef __attribute__((ext_vector_type(4))) float f4v;

// ---- fp32 -> bf16 split helpers (RNE) ----
__device__ __forceinline__ unsigned short bf16_rne(float f) {
    unsigned u = __float_as_uint(f);
    unsigned r = u + 0x7fffu + ((u >> 16) & 1u);
    return (unsigned short)(r >> 16);
}
__device__ __forceinline__ float bf16_to_f(unsigned short h) {
    return __uint_as_float((unsigned)h << 16);
}

// ---- init: deg = 0, pooled = 0, cnt = 0 ----
__global__ void init_kernel(int* __restrict__ deg, float* __restrict__ pooled,
                            float* __restrict__ cnt) {
    int i = blockIdx.x * blockDim.x + threadIdx.x;
    if (i < N_NODES) deg[i] = 0;
    if (i < NG * CPH) pooled[i] = 0.0f;
    if (i < NG) cnt[i] = 0.0f;
}

// ---- fp32 -> (hi, lo) bf16 planes ----
__global__ void cvt_split(const float* __restrict__ src,
                          unsigned short* __restrict__ hi,
                          unsigned short* __restrict__ lo, int n) {
    for (int i = blockIdx.x * blockDim.x + threadIdx.x; i < n;
         i += gridDim.x * blockDim.x) {
        float f = src[i];
        unsigned short h = bf16_rne(f);
        hi[i] = h;
        lo[i] = bf16_rne(f - bf16_to_f(h));
    }
}

// ---- split-bf16 MFMA GEMM: C[m][n] = act( sum_k A[m][k]*W[n][k] + bias[n] )
// A from (Ahi,Alo) planes, or converted on the fly from fp32 Af when Ahi==null.
// Tile 128x128, 4 waves (2x2), each wave 4x4 fragments of 16x16x32.
__global__ __launch_bounds__(256) void mfma_gemm(
    const unsigned short* __restrict__ Ahi, const unsigned short* __restrict__ Alo,
    const float* __restrict__ Af,
    const unsigned short* __restrict__ Whi, const unsigned short* __restrict__ Wlo,
    const float* __restrict__ bias, float* __restrict__ C,
    int M, int NN, int K, int act)
{
    const int t    = threadIdx.x;
    const int wave = t >> 6, lane = t & 63;
    const int wr = wave >> 1, wc = wave & 1;
    const int l15 = lane & 15, lg = lane >> 4;
    const int m0 = blockIdx.x * 128 + wr * 64;
    const int n0 = blockIdx.y * 128 + wc * 64;
    const int koff = lg * 8;

    int rowA[4], colB[4];
    #pragma unroll
    for (int i = 0; i < 4; ++i) {
        int r = m0 + i * 16 + l15;
        rowA[i] = r < M ? r : M - 1;
    }
    #pragma unroll
    for (int j = 0; j < 4; ++j) colB[j] = n0 + j * 16 + l15;

    float bj[4];
    #pragma unroll
    for (int j = 0; j < 4; ++j) bj[j] = bias[colB[j]];

    f4v acc[4][4];
    #pragma unroll
    for (int i = 0; i < 4; ++i)
        #pragma unroll
        for (int j = 0; j < 4; ++j)
            acc[i][j] = (f4v){0.f, 0.f, 0.f, 0.f};

    for (int k0 = 0; k0 < K; k0 += 32) {
        s8v ah[4], al[4], bh[4], bl[4];
        if (Ahi) {
            #pragma unroll
            for (int i = 0; i < 4; ++i) {
                size_t off = (size_t)rowA[i] * K + k0 + koff;
                ah[i] = *(const s8v*)&Ahi[off];
                al[i] = *(const s8v*)&Alo[off];
            }
        } else {
            #pragma unroll
            for (int i = 0; i < 4; ++i) {
                const float* p = &Af[(size_t)rowA[i] * K + k0 + koff];
                f4v f0 = *(const f4v*)p;
                f4v f1 = *(const f4v*)(p + 4);
                #pragma unroll
                for (int e = 0; e < 4; ++e) {
                    unsigned short h0 = bf16_rne(f0[e]);
                    ah[i][e] = (short)h0;
                    al[i][e] = (short)bf16_rne(f0[e] - bf16_to_f(h0));
                    unsigned short h1 = bf16_rne(f1[e]);
                    ah[i][e + 4] = (short)h1;
                    al[i][e + 4] = (short)bf16_rne(f1[e] - bf16_to_f(h1));
                }
            }
        }
        #pragma unroll
        for (int j = 0; j < 4; ++j) {
            size_t off = (size_t)colB[j] * K + k0 + koff;
            bh[j] = *(const s8v*)&Whi[off];
            bl[j] = *(const s8v*)&Wlo[off];
        }
        #pragma unroll
        for (int i = 0; i < 4; ++i)
            #pragma unroll
            for (int j = 0; j < 4; ++j) {
                acc[i][j] = __builtin_amdgcn_mfma_f32_16x16x32_bf16(ah[i], bh[j], acc[i][j], 0, 0, 0);
                acc[i][j] = __builtin_amdgcn_mfma_f32_16x16x32_bf16(ah[i], bl[j], acc[i][j], 0, 0, 0);
                acc[i][j] = __builtin_amdgcn_mfma_f32_16x16x32_bf16(al[i], bh[j], acc[i][j], 0, 0, 0);
            }
    }

    #pragma unroll
    for (int i = 0; i < 4; ++i) {
        #pragma unroll
        for (int r = 0; r < 4; ++r) {
            int row = m0 + i * 16 + lg * 4 + r;
            if (row >= M) continue;
            #pragma unroll
            for (int j = 0; j < 4; ++j) {
                float v = acc[i][j][r] + bj[j];
                if (act == 1) v = v > 0.0f ? v : expm1f(v);   // ELU
                C[(size_t)row * NN + colB[j]] = v;
            }
        }
    }
}

// ---- CSR build: histogram ----
__global__ void hist_kernel(const int* __restrict__ ei, int* __restrict__ deg) {
    for (int e = blockIdx.x * blockDim.x + threadIdx.x; e < ETOT;
         e += gridDim.x * blockDim.x) {
        int dst = (e < N_EDGES) ? ei[N_EDGES + e] : (e - N_EDGES);
        atomicAdd(&deg[dst], 1);
    }
}

// ---- CSR build: single-block exclusive scan -> rowptr, wof ----
__global__ __launch_bounds__(256) void scan_kernel(
    const int* __restrict__ deg, int* __restrict__ rowptr, int* __restrict__ wof)
{
    __shared__ int sbuf[256];
    __shared__ int carry;
    const int t = threadIdx.x;
    if (t == 0) { carry = 0; rowptr[0] = 0; }
    __syncthreads();
    for (int base = 0; base < N_NODES; base += 256) {
        int i = base + t;
        int orig = (i < N_NODES) ? deg[i] : 0;
        sbuf[t] = orig;
        __syncthreads();
        #pragma unroll
        for (int off = 1; off < 256; off <<= 1) {
            int add = (t >= off) ? sbuf[t - off] : 0;
            __syncthreads();
            sbuf[t] += add;
            __syncthreads();
        }
        int inc = sbuf[t] + carry;
        if (i < N_NODES) { rowptr[i + 1] = inc; wof[i] = inc - orig; }
        __syncthreads();
        if (t == 255) carry = inc;
        __syncthreads();
    }
}

// ---- CSR build: scatter edge src ids ----
__global__ void scatter_kernel(const int* __restrict__ ei, int* __restrict__ wof,
                               int* __restrict__ csr_src)
{
    for (int e = blockIdx.x * blockDim.x + threadIdx.x; e < ETOT;
         e += gridDim.x * blockDim.x) {
        int src, dst;
        if (e < N_EDGES) { src = ei[e]; dst = ei[N_EDGES + e]; }
        else             { src = dst = e - N_EDGES; }
        int p = atomicAdd(&wof[dst], 1);
        csr_src[p] = src;
    }
}

// ---- fused logits + online segment softmax + aggregation, one block per dst ----
__global__ __launch_bounds__(256) void agg_fused(
    const float* __restrict__ xl, const float* __restrict__ xr,
    const float* __restrict__ att,
    const int* __restrict__ rowptr, const int* __restrict__ csr_src,
    float* __restrict__ outc)
{
    const int dst = blockIdx.x;
    const int t = threadIdx.x;
    const int beg = rowptr[dst], end = rowptr[dst + 1];

    const f4v b = *(const f4v*)&xr[(size_t)dst * HCH + t * 4];
    const f4v w = *(const f4v*)&att[t * 4];

    float m = -__builtin_inff(), s = 0.0f;
    f4v acc = {0.f, 0.f, 0.f, 0.f};

    for (int j = beg; j < end; ++j) {
        const int src = csr_src[j];
        const f4v v = *(const f4v*)&xl[(size_t)src * HCH + t * 4];
        float e0 = v[0] + b[0]; e0 = e0 > 0.f ? e0 : 0.2f * e0;
        float e1 = v[1] + b[1]; e1 = e1 > 0.f ? e1 : 0.2f * e1;
        float e2 = v[2] + b[2]; e2 = e2 > 0.f ? e2 : 0.2f * e2;
        float e3 = v[3] + b[3]; e3 = e3 > 0.f ? e3 : 0.2f * e3;
        float p = e0 * w[0] + e1 * w[1] + e2 * w[2] + e3 * w[3];
        #pragma unroll
        for (int off = 16; off; off >>= 1) p += __shfl_xor(p, off, 32);

        float mn    = fmaxf(m, p);
        float scale = __expf(m - mn);   // first iter: exp(-inf) = 0
        float pw    = __expf(p - mn);
        s = s * scale + pw;
        acc = acc * scale + v * pw;
        m = mn;
    }

    const float inv = 1.0f / (s + 1e-16f);
    float* o = &outc[(size_t)dst * HCH + t * 4];
    f4v cur = *(f4v*)o;
    cur += acc * inv;
    *(f4v*)o = cur;
}

// ---- mean-pool accumulation ----
__global__ __launch_bounds__(128) void pool_kernel(
    const float* __restrict__ h, const int* __restrict__ batch,
    float* __restrict__ pooled, float* __restrict__ cnt)
{
    const int n = blockIdx.x;
    const int t = threadIdx.x;
    const int g = batch[n];
    atomicAdd(&pooled[g * CPH + t], h[(size_t)n * CPH + t]);
    if (t == 0) atomicAdd(&cnt[g], 1.0f);
}

// ---- MLP head: one thread per graph ----
__global__ __launch_bounds__(64) void head_kernel(
    const float* __restrict__ pooled, const float* __restrict__ cnt,
    const float* __restrict__ W1, const float* __restrict__ b1,
    const float* __restrict__ W2, const float* __restrict__ b2,
    const float* __restrict__ W3, const float* __restrict__ b3,
    float* __restrict__ out)
{
    const int g = threadIdx.x;
    const float inv = 1.0f / fmaxf(cnt[g], 1.0f);

    float y1[16];
    for (int j = 0; j < 16; ++j) {
        float s = 0.0f;
        for (int k = 0; k < CPH; ++k) s += W1[j * CPH + k] * pooled[g * CPH + k];
        s = s * inv + b1[j];
        y1[j] = fmaxf(s, 0.0f);
    }
    float y2[32];
    for (int j = 0; j < 32; ++j) {
        float s = b2[j];
        for (int k = 0; k < 16; ++k) s += W2[j * 16 + k] * y1[k];
        y2[j] = fmaxf(s, 0.0f);
    }
    for (int u = 0; u < 5; ++u) {
        float s = b3[u];
        for (int k = 0; k < 32; ++k) s += W3[u * 32 + k] * y2[k];
        out[g * 5 + u] = s;
    }
}

extern "C" void kernel_launch(void* const* d_in, const int* in_sizes, int n_in,
                              void* d_out, int out_size, void* d_ws, size_t ws_size,
                              hipStream_t stream)
{
    const float* x         = (const float*)d_in[0];
    const int*   ei        = (const int*)  d_in[1];
    const int*   batch     = (const int*)  d_in[2];
    const float* Wl        = (const float*)d_in[3];
    const float* bl        = (const float*)d_in[4];
    const float* Wr        = (const float*)d_in[5];
    const float* br        = (const float*)d_in[6];
    const float* att       = (const float*)d_in[7];
    const float* Wres      = (const float*)d_in[8];
    const float* bias_conv = (const float*)d_in[9];
    const float* Wlin      = (const float*)d_in[10];
    const float* blin      = (const float*)d_in[11];
    const float* W1        = (const float*)d_in[12];
    const float* b1        = (const float*)d_in[13];
    const float* W2        = (const float*)d_in[14];
    const float* b2        = (const float*)d_in[15];
    const float* W3        = (const float*)d_in[16];
    const float* b3        = (const float*)d_in[17];
    float* out = (float*)d_out;

    // ---- workspace layout (floats) ----
    float* xl     = (float*)d_ws;                     // 20.48M
    float* xr     = xl   + (size_t)N_NODES * HCH;     // 20.48M
    float* outc   = xr   + (size_t)N_NODES * HCH;     // 20.48M
    float* hbuf   = outc + (size_t)N_NODES * HCH;     // 2.56M  (CSR aliases below)
    float* pooled = hbuf + (size_t)N_NODES * CPH;
    float* cnt    = pooled + (size_t)NG * CPH;
    unsigned short* x_hi  = (unsigned short*)(cnt + NG);          // 2.56M u16
    unsigned short* x_lo  = x_hi  + (size_t)N_NODES * IN_CH;      // 2.56M u16
    unsigned short* wl_hi = x_lo  + (size_t)N_NODES * IN_CH;      // 131072 u16 each below
    unsigned short* wl_lo = wl_hi + HCH * IN_CH;
    unsigned short* wr_hi = wl_lo + HCH * IN_CH;
    unsigned short* wr_lo = wr_hi + HCH * IN_CH;
    unsigned short* ws_hi = wr_lo + HCH * IN_CH;
    unsigned short* ws_lo = ws_hi + HCH * IN_CH;
    unsigned short* wn_hi = ws_lo + HCH * IN_CH;
    unsigned short* wn_lo = wn_hi + CPH * HCH;

    // CSR structures alias hbuf (dead before Wlin GEMM writes hbuf)
    int* deg     = (int*)hbuf;                        // N
    int* rowptr  = deg + N_NODES;                     // N+1
    int* wof     = rowptr + N_NODES + 1;              // N
    int* csr_src = wof + N_NODES;                     // ETOT  (740K ints < 2.56M floats)

    init_kernel<<<(N_NODES + 255) / 256, 256, 0, stream>>>(deg, pooled, cnt);

    // bf16 hi/lo planes
    cvt_split<<<2048, 256, 0, stream>>>(x,    x_hi,  x_lo,  N_NODES * IN_CH);
    cvt_split<<<128,  256, 0, stream>>>(Wl,   wl_hi, wl_lo, HCH * IN_CH);
    cvt_split<<<128,  256, 0, stream>>>(Wr,   wr_hi, wr_lo, HCH * IN_CH);
    cvt_split<<<128,  256, 0, stream>>>(Wres, ws_hi, ws_lo, HCH * IN_CH);
    cvt_split<<<128,  256, 0, stream>>>(Wlin, wn_hi, wn_lo, CPH * HCH);

    // three projections: [20000,128] @ [1024,128]^T
    dim3 gp((N_NODES + 127) / 128, HCH / 128);
    mfma_gemm<<<gp, 256, 0, stream>>>(x_hi, x_lo, nullptr, wl_hi, wl_lo, bl,        xl,   N_NODES, HCH, IN_CH, 0);
    mfma_gemm<<<gp, 256, 0, stream>>>(x_hi, x_lo, nullptr, wr_hi, wr_lo, br,        xr,   N_NODES, HCH, IN_CH, 0);
    mfma_gemm<<<gp, 256, 0, stream>>>(x_hi, x_lo, nullptr, ws_hi, ws_lo, bias_conv, outc, N_NODES, HCH, IN_CH, 0);

    // CSR by destination
    hist_kernel<<<1024, 256, 0, stream>>>(ei, deg);
    scan_kernel<<<1, 256, 0, stream>>>(deg, rowptr, wof);
    scatter_kernel<<<1024, 256, 0, stream>>>(ei, wof, csr_src);

    // fused logits + online softmax + weighted aggregation (adds into outc)
    agg_fused<<<N_NODES, 256, 0, stream>>>(xl, xr, att, rowptr, csr_src, outc);

    // Linear(1024->128) + ELU, A converted from fp32 on the fly
    dim3 gl((N_NODES + 127) / 128, 1);
    mfma_gemm<<<gl, 256, 0, stream>>>(nullptr, nullptr, outc, wn_hi, wn_lo, blin, hbuf, N_NODES, CPH, HCH, 1);

    pool_kernel<<<N_NODES, 128, 0, stream>>>(hbuf, batch, pooled, cnt);

    head_kernel<<<1, 64, 0, stream>>>(pooled, cnt, W1, b1, W2, b2, W3, b3, out);
}

// Round 5
// 713.086 us; speedup vs baseline: 7.9763x; 1.1648x over previous
//
#include <hip/hip_runtime.h>
#include <hip/hip_bf16.h>
#include <math.h>

#define N_NODES 20000
#define N_EDGES 320000
#define IN_CH   128
#define HEADS   8
#define CPH     128
#define HCH     1024
#define NG      64
#define ETOT    (N_EDGES + N_NODES)

typedef __attribute__((ext_vector_type(8))) short s8v;
typedef __attribute__((ext_vector_type(4))) float f4v;
typedef __attribute__((ext_vector_type(4))) unsigned short u16x4;

// ---- fp32 -> bf16 split helpers (RNE) ----
__device__ __forceinline__ unsigned short bf16_rne(float f) {
    unsigned u = __float_as_uint(f);
    unsigned r = u + 0x7fffu + ((u >> 16) & 1u);
    return (unsigned short)(r >> 16);
}
__device__ __forceinline__ float bf16_to_f(unsigned short h) {
    return __uint_as_float((unsigned)h << 16);
}

// ---- zero deg ----
__global__ void init_kernel(int* __restrict__ deg) {
    int i = blockIdx.x * blockDim.x + threadIdx.x;
    if (i < N_NODES) deg[i] = 0;
}

// ---- fp32 -> (hi,lo) bf16 planes for x, Wl, Wr, Wlin in one kernel ----
__global__ void cvt_all(const float* __restrict__ x,  const float* __restrict__ Wl,
                        const float* __restrict__ Wr, const float* __restrict__ Wlin,
                        unsigned short* __restrict__ xhi,  unsigned short* __restrict__ xlo,
                        unsigned short* __restrict__ wlhi, unsigned short* __restrict__ wllo,
                        unsigned short* __restrict__ wrhi, unsigned short* __restrict__ wrlo,
                        unsigned short* __restrict__ wnhi, unsigned short* __restrict__ wnlo)
{
    const int NX = N_NODES * IN_CH, NW = HCH * IN_CH;
    const int TOT = NX + 3 * NW;
    for (int i = blockIdx.x * blockDim.x + threadIdx.x; i < TOT;
         i += gridDim.x * blockDim.x) {
        const float* s; unsigned short *hi, *lo; int k;
        if (i < NX)               { s = x;    hi = xhi;  lo = xlo;  k = i; }
        else if (i < NX + NW)     { s = Wl;   hi = wlhi; lo = wllo; k = i - NX; }
        else if (i < NX + 2 * NW) { s = Wr;   hi = wrhi; lo = wrlo; k = i - NX - NW; }
        else                      { s = Wlin; hi = wnhi; lo = wnlo; k = i - NX - 2 * NW; }
        float f = s[k];
        unsigned short h = bf16_rne(f);
        hi[k] = h;
        lo[k] = bf16_rne(f - bf16_to_f(h));
    }
}

// ---- Wcomb = Wlin @ Wres  (128x128), bcomb = blin + Wlin @ bias_conv ----
__global__ __launch_bounds__(128) void wcomb_kernel(
    const float* __restrict__ Wlin, const float* __restrict__ Wres,
    const float* __restrict__ bias_conv, const float* __restrict__ blin,
    unsigned short* __restrict__ wchi, unsigned short* __restrict__ wclo,
    float* __restrict__ bcomb)
{
    const int j = blockIdx.x;    // output row (0..127)
    const int t = threadIdx.x;   // output col
    float s = 0.0f, pb = 0.0f;
    for (int m = 0; m < HCH; ++m) {
        float wl = Wlin[j * HCH + m];
        s  += wl * Wres[m * IN_CH + t];
        pb += wl * bias_conv[m];
    }
    unsigned short h = bf16_rne(s);
    wchi[j * IN_CH + t] = h;
    wclo[j * IN_CH + t] = bf16_rne(s - bf16_to_f(h));
    if (t == 0) bcomb[j] = blin[j] + pb;
}

// ---- split-bf16 MFMA GEMM: C = A @ W.T + bias. Tile 128x128, 4 waves. ----
__global__ __launch_bounds__(256) void mfma_gemm(
    const unsigned short* __restrict__ Ahi, const unsigned short* __restrict__ Alo,
    const unsigned short* __restrict__ Whi, const unsigned short* __restrict__ Wlo,
    const float* __restrict__ bias, float* __restrict__ C,
    int M, int NN, int K)
{
    const int t    = threadIdx.x;
    const int wave = t >> 6, lane = t & 63;
    const int wr = wave >> 1, wc = wave & 1;
    const int l15 = lane & 15, lg = lane >> 4;
    const int m0 = blockIdx.x * 128 + wr * 64;
    const int n0 = blockIdx.y * 128 + wc * 64;
    const int koff = lg * 8;

    int rowA[4], colB[4];
    #pragma unroll
    for (int i = 0; i < 4; ++i) { int r = m0 + i * 16 + l15; rowA[i] = r < M ? r : M - 1; }
    #pragma unroll
    for (int j = 0; j < 4; ++j) colB[j] = n0 + j * 16 + l15;

    float bj[4];
    #pragma unroll
    for (int j = 0; j < 4; ++j) bj[j] = bias[colB[j]];

    f4v acc[4][4];
    #pragma unroll
    for (int i = 0; i < 4; ++i)
        #pragma unroll
        for (int j = 0; j < 4; ++j) acc[i][j] = (f4v){0.f, 0.f, 0.f, 0.f};

    for (int k0 = 0; k0 < K; k0 += 32) {
        s8v ah[4], al[4], bh[4], bl[4];
        #pragma unroll
        for (int i = 0; i < 4; ++i) {
            size_t off = (size_t)rowA[i] * K + k0 + koff;
            ah[i] = *(const s8v*)&Ahi[off];
            al[i] = *(const s8v*)&Alo[off];
        }
        #pragma unroll
        for (int j = 0; j < 4; ++j) {
            size_t off = (size_t)colB[j] * K + k0 + koff;
            bh[j] = *(const s8v*)&Whi[off];
            bl[j] = *(const s8v*)&Wlo[off];
        }
        #pragma unroll
        for (int i = 0; i < 4; ++i)
            #pragma unroll
            for (int j = 0; j < 4; ++j) {
                acc[i][j] = __builtin_amdgcn_mfma_f32_16x16x32_bf16(ah[i], bh[j], acc[i][j], 0, 0, 0);
                acc[i][j] = __builtin_amdgcn_mfma_f32_16x16x32_bf16(ah[i], bl[j], acc[i][j], 0, 0, 0);
                acc[i][j] = __builtin_amdgcn_mfma_f32_16x16x32_bf16(al[i], bh[j], acc[i][j], 0, 0, 0);
            }
    }

    #pragma unroll
    for (int i = 0; i < 4; ++i)
        #pragma unroll
        for (int r = 0; r < 4; ++r) {
            int row = m0 + i * 16 + lg * 4 + r;
            if (row >= M) continue;
            #pragma unroll
            for (int j = 0; j < 4; ++j)
                C[(size_t)row * NN + colB[j]] = acc[i][j][r] + bj[j];
        }
}

// ---- fused final GEMM: C = ELU( A1@B1.T (K1) + A2@B2.T (K2) + bias ), NN=128 ----
__global__ __launch_bounds__(256) void mfma_gemm2(
    const unsigned short* __restrict__ A1hi, const unsigned short* __restrict__ A1lo,
    const unsigned short* __restrict__ B1hi, const unsigned short* __restrict__ B1lo, int K1,
    const unsigned short* __restrict__ A2hi, const unsigned short* __restrict__ A2lo,
    const unsigned short* __restrict__ B2hi, const unsigned short* __restrict__ B2lo, int K2,
    const float* __restrict__ bias, float* __restrict__ C, int M, int NN)
{
    const int t    = threadIdx.x;
    const int wave = t >> 6, lane = t & 63;
    const int wr = wave >> 1, wc = wave & 1;
    const int l15 = lane & 15, lg = lane >> 4;
    const int m0 = blockIdx.x * 128 + wr * 64;
    const int n0 = wc * 64;
    const int koff = lg * 8;

    int rowA[4], colB[4];
    #pragma unroll
    for (int i = 0; i < 4; ++i) { int r = m0 + i * 16 + l15; rowA[i] = r < M ? r : M - 1; }
    #pragma unroll
    for (int j = 0; j < 4; ++j) colB[j] = n0 + j * 16 + l15;

    float bj[4];
    #pragma unroll
    for (int j = 0; j < 4; ++j) bj[j] = bias[colB[j]];

    f4v acc[4][4];
    #pragma unroll
    for (int i = 0; i < 4; ++i)
        #pragma unroll
        for (int j = 0; j < 4; ++j) acc[i][j] = (f4v){0.f, 0.f, 0.f, 0.f};

    for (int k0 = 0; k0 < K1; k0 += 32) {
        s8v ah[4], al[4], bh[4], bl[4];
        #pragma unroll
        for (int i = 0; i < 4; ++i) {
            size_t off = (size_t)rowA[i] * K1 + k0 + koff;
            ah[i] = *(const s8v*)&A1hi[off];
            al[i] = *(const s8v*)&A1lo[off];
        }
        #pragma unroll
        for (int j = 0; j < 4; ++j) {
            size_t off = (size_t)colB[j] * K1 + k0 + koff;
            bh[j] = *(const s8v*)&B1hi[off];
            bl[j] = *(const s8v*)&B1lo[off];
        }
        #pragma unroll
        for (int i = 0; i < 4; ++i)
            #pragma unroll
            for (int j = 0; j < 4; ++j) {
                acc[i][j] = __builtin_amdgcn_mfma_f32_16x16x32_bf16(ah[i], bh[j], acc[i][j], 0, 0, 0);
                acc[i][j] = __builtin_amdgcn_mfma_f32_16x16x32_bf16(ah[i], bl[j], acc[i][j], 0, 0, 0);
                acc[i][j] = __builtin_amdgcn_mfma_f32_16x16x32_bf16(al[i], bh[j], acc[i][j], 0, 0, 0);
            }
    }
    for (int k0 = 0; k0 < K2; k0 += 32) {
        s8v ah[4], al[4], bh[4], bl[4];
        #pragma unroll
        for (int i = 0; i < 4; ++i) {
            size_t off = (size_t)rowA[i] * K2 + k0 + koff;
            ah[i] = *(const s8v*)&A2hi[off];
            al[i] = *(const s8v*)&A2lo[off];
        }
        #pragma unroll
        for (int j = 0; j < 4; ++j) {
            size_t off = (size_t)colB[j] * K2 + k0 + koff;
            bh[j] = *(const s8v*)&B2hi[off];
            bl[j] = *(const s8v*)&B2lo[off];
        }
        #pragma unroll
        for (int i = 0; i < 4; ++i)
            #pragma unroll
            for (int j = 0; j < 4; ++j) {
                acc[i][j] = __builtin_amdgcn_mfma_f32_16x16x32_bf16(ah[i], bh[j], acc[i][j], 0, 0, 0);
                acc[i][j] = __builtin_amdgcn_mfma_f32_16x16x32_bf16(ah[i], bl[j], acc[i][j], 0, 0, 0);
                acc[i][j] = __builtin_amdgcn_mfma_f32_16x16x32_bf16(al[i], bh[j], acc[i][j], 0, 0, 0);
            }
    }

    #pragma unroll
    for (int i = 0; i < 4; ++i)
        #pragma unroll
        for (int r = 0; r < 4; ++r) {
            int row = m0 + i * 16 + lg * 4 + r;
            if (row >= M) continue;
            #pragma unroll
            for (int j = 0; j < 4; ++j) {
                float v = acc[i][j][r] + bj[j];
                v = v > 0.0f ? v : expm1f(v);   // ELU
                C[(size_t)row * NN + colB[j]] = v;
            }
        }
}

// ---- CSR build: histogram ----
__global__ void hist_kernel(const int* __restrict__ ei, int* __restrict__ deg) {
    for (int e = blockIdx.x * blockDim.x + threadIdx.x; e < ETOT;
         e += gridDim.x * blockDim.x) {
        int dst = (e < N_EDGES) ? ei[N_EDGES + e] : (e - N_EDGES);
        atomicAdd(&deg[dst], 1);
    }
}

// ---- CSR build: single-block scan with wave shuffles ----
__global__ __launch_bounds__(256) void scan_kernel(
    const int* __restrict__ deg, int* __restrict__ rowptr, int* __restrict__ wof)
{
    __shared__ int wsum[4];
    __shared__ int carry_s;
    const int t = threadIdx.x, wave = t >> 6, lane = t & 63;
    if (t == 0) { carry_s = 0; rowptr[0] = 0; }
    __syncthreads();
    for (int base = 0; base < N_NODES; base += 256) {
        int i = base + t;
        int orig = (i < N_NODES) ? deg[i] : 0;
        int v = orig;
        #pragma unroll
        for (int off = 1; off < 64; off <<= 1) {
            int u = __shfl_up(v, off, 64);
            if (lane >= off) v += u;
        }
        if (lane == 63) wsum[wave] = v;
        __syncthreads();
        int woff = carry_s;
        #pragma unroll
        for (int w = 0; w < 4; ++w) if (w < wave) woff += wsum[w];
        int inc = v + woff;
        if (i < N_NODES) { rowptr[i + 1] = inc; wof[i] = inc - orig; }
        __syncthreads();
        if (t == 255) carry_s = inc;
        __syncthreads();
    }
}

// ---- CSR build: scatter edge src ids ----
__global__ void scatter_kernel(const int* __restrict__ ei, int* __restrict__ wof,
                               int* __restrict__ csr_src)
{
    for (int e = blockIdx.x * blockDim.x + threadIdx.x; e < ETOT;
         e += gridDim.x * blockDim.x) {
        int src, dst;
        if (e < N_EDGES) { src = ei[e]; dst = ei[N_EDGES + e]; }
        else             { src = dst = e - N_EDGES; }
        int p = atomicAdd(&wof[dst], 1);
        csr_src[p] = src;
    }
}

// ---- fused logits + online softmax + aggregation -> bf16 hi/lo planes ----
__global__ __launch_bounds__(256) void agg_fused(
    const float* __restrict__ xl, const float* __restrict__ xr,
    const float* __restrict__ att,
    const int* __restrict__ rowptr, const int* __restrict__ csr_src,
    unsigned short* __restrict__ agg_hi, unsigned short* __restrict__ agg_lo)
{
    const int dst = blockIdx.x;
    const int t = threadIdx.x;
    const int beg = rowptr[dst], end = rowptr[dst + 1];

    const f4v b = *(const f4v*)&xr[(size_t)dst * HCH + t * 4];
    const f4v w = *(const f4v*)&att[t * 4];

    float m = -__builtin_inff(), s = 0.0f;
    f4v acc = {0.f, 0.f, 0.f, 0.f};

    for (int j = beg; j < end; ++j) {
        const int src = csr_src[j];
        const f4v v = *(const f4v*)&xl[(size_t)src * HCH + t * 4];
        float e0 = v[0] + b[0]; e0 = e0 > 0.f ? e0 : 0.2f * e0;
        float e1 = v[1] + b[1]; e1 = e1 > 0.f ? e1 : 0.2f * e1;
        float e2 = v[2] + b[2]; e2 = e2 > 0.f ? e2 : 0.2f * e2;
        float e3 = v[3] + b[3]; e3 = e3 > 0.f ? e3 : 0.2f * e3;
        float p = e0 * w[0] + e1 * w[1] + e2 * w[2] + e3 * w[3];
        #pragma unroll
        for (int off = 16; off; off >>= 1) p += __shfl_xor(p, off, 32);

        float mn    = fmaxf(m, p);
        float scale = __expf(m - mn);
        float pw    = __expf(p - mn);
        s = s * scale + pw;
        acc = acc * scale + v * pw;
        m = mn;
    }

    const float inv = 1.0f / (s + 1e-16f);
    f4v r = acc * inv;
    u16x4 hv, lv;
    #pragma unroll
    for (int e = 0; e < 4; ++e) {
        unsigned short h = bf16_rne(r[e]);
        hv[e] = h;
        lv[e] = bf16_rne(r[e] - bf16_to_f(h));
    }
    *(u16x4*)&agg_hi[(size_t)dst * HCH + t * 4] = hv;
    *(u16x4*)&agg_lo[(size_t)dst * HCH + t * 4] = lv;
}

// ---- segmented mean pool (batch is sorted) ----
__global__ __launch_bounds__(128) void pool_kernel2(
    const float* __restrict__ h, const int* __restrict__ batch,
    float* __restrict__ pooled)
{
    const int g = blockIdx.x;
    const int t = threadIdx.x;
    int lo = 0, hi = N_NODES;
    while (lo < hi) { int mid = (lo + hi) >> 1; if (batch[mid] <  g) lo = mid + 1; else hi = mid; }
    const int s0 = lo;
    hi = N_NODES;
    while (lo < hi) { int mid = (lo + hi) >> 1; if (batch[mid] <= g) lo = mid + 1; else hi = mid; }
    const int s1 = lo;

    float acc = 0.0f;
    for (int n = s0; n < s1; ++n) acc += h[(size_t)n * CPH + t];
    pooled[g * CPH + t] = acc / fmaxf((float)(s1 - s0), 1.0f);
}

// ---- MLP head: one thread per graph ----
__global__ __launch_bounds__(64) void head_kernel(
    const float* __restrict__ pooled,
    const float* __restrict__ W1, const float* __restrict__ b1,
    const float* __restrict__ W2, const float* __restrict__ b2,
    const float* __restrict__ W3, const float* __restrict__ b3,
    float* __restrict__ out)
{
    const int g = threadIdx.x;
    float y1[16];
    for (int j = 0; j < 16; ++j) {
        float s = b1[j];
        for (int k = 0; k < CPH; ++k) s += W1[j * CPH + k] * pooled[g * CPH + k];
        y1[j] = fmaxf(s, 0.0f);
    }
    float y2[32];
    for (int j = 0; j < 32; ++j) {
        float s = b2[j];
        for (int k = 0; k < 16; ++k) s += W2[j * 16 + k] * y1[k];
        y2[j] = fmaxf(s, 0.0f);
    }
    for (int u = 0; u < 5; ++u) {
        float s = b3[u];
        for (int k = 0; k < 32; ++k) s += W3[u * 32 + k] * y2[k];
        out[g * 5 + u] = s;
    }
}

extern "C" void kernel_launch(void* const* d_in, const int* in_sizes, int n_in,
                              void* d_out, int out_size, void* d_ws, size_t ws_size,
                              hipStream_t stream)
{
    const float* x         = (const float*)d_in[0];
    const int*   ei        = (const int*)  d_in[1];
    const int*   batch     = (const int*)  d_in[2];
    const float* Wl        = (const float*)d_in[3];
    const float* bl        = (const float*)d_in[4];
    const float* Wr        = (const float*)d_in[5];
    const float* br        = (const float*)d_in[6];
    const float* att       = (const float*)d_in[7];
    const float* Wres      = (const float*)d_in[8];
    const float* bias_conv = (const float*)d_in[9];
    const float* Wlin      = (const float*)d_in[10];
    const float* blin      = (const float*)d_in[11];
    const float* W1        = (const float*)d_in[12];
    const float* b1        = (const float*)d_in[13];
    const float* W2        = (const float*)d_in[14];
    const float* b2        = (const float*)d_in[15];
    const float* W3        = (const float*)d_in[16];
    const float* b3        = (const float*)d_in[17];
    float* out = (float*)d_out;

    // ---- workspace layout (total 267.9 MB < 256 MiB limit) ----
    // ws_size is ~256 MiB: R3's 268.37 MB layout worked, R4's 269.51 MB crashed.
    // CSR aliases hbuf (CSR dead before mfma_gemm2 writes hbuf).
    float* xl     = (float*)d_ws;                               // 20.48M f
    float* xr     = xl + (size_t)N_NODES * HCH;                 // 20.48M f
    unsigned short* agg_hi = (unsigned short*)(xr + (size_t)N_NODES * HCH); // 20.48M u16
    unsigned short* agg_lo = agg_hi + (size_t)N_NODES * HCH;    // 20.48M u16
    float* hbuf   = (float*)(agg_lo + (size_t)N_NODES * HCH);   // 2.56M f
    float* pooled = hbuf + (size_t)N_NODES * CPH;               // 8192 f
    float* bcomb  = pooled + NG * CPH;                          // 128 f
    unsigned short* x_hi  = (unsigned short*)(bcomb + 128);     // 2.56M u16
    unsigned short* x_lo  = x_hi  + (size_t)N_NODES * IN_CH;    // 2.56M u16
    unsigned short* wl_hi = x_lo  + (size_t)N_NODES * IN_CH;    // 131072 u16 each
    unsigned short* wl_lo = wl_hi + HCH * IN_CH;
    unsigned short* wr_hi = wl_lo + HCH * IN_CH;
    unsigned short* wr_lo = wr_hi + HCH * IN_CH;
    unsigned short* wn_hi = wr_lo + HCH * IN_CH;
    unsigned short* wn_lo = wn_hi + CPH * HCH;
    unsigned short* wc_hi = wn_lo + CPH * HCH;                  // 16384 u16
    unsigned short* wc_lo = wc_hi + CPH * IN_CH;

    // CSR structures alias hbuf (400,001 ints = 1.6 MB < 10.24 MB region)
    int* deg     = (int*)hbuf;                                  // N
    int* rowptr  = deg + N_NODES;                               // N+1
    int* wof     = rowptr + N_NODES + 1;                        // N
    int* csr_src = wof + N_NODES;                               // ETOT

    init_kernel<<<(N_NODES + 255) / 256, 256, 0, stream>>>(deg);

    cvt_all<<<1536, 256, 0, stream>>>(x, Wl, Wr, Wlin,
                                      x_hi, x_lo, wl_hi, wl_lo,
                                      wr_hi, wr_lo, wn_hi, wn_lo);

    wcomb_kernel<<<CPH, 128, 0, stream>>>(Wlin, Wres, bias_conv, blin, wc_hi, wc_lo, bcomb);

    dim3 gp((N_NODES + 127) / 128, HCH / 128);
    mfma_gemm<<<gp, 256, 0, stream>>>(x_hi, x_lo, wl_hi, wl_lo, bl, xl, N_NODES, HCH, IN_CH);
    mfma_gemm<<<gp, 256, 0, stream>>>(x_hi, x_lo, wr_hi, wr_lo, br, xr, N_NODES, HCH, IN_CH);

    hist_kernel<<<1024, 256, 0, stream>>>(ei, deg);
    scan_kernel<<<1, 256, 0, stream>>>(deg, rowptr, wof);
    scatter_kernel<<<1024, 256, 0, stream>>>(ei, wof, csr_src);

    agg_fused<<<N_NODES, 256, 0, stream>>>(xl, xr, att, rowptr, csr_src, agg_hi, agg_lo);

    dim3 g2((N_NODES + 127) / 128, 1);
    mfma_gemm2<<<g2, 256, 0, stream>>>(agg_hi, agg_lo, wn_hi, wn_lo, HCH,
                                       x_hi, x_lo, wc_hi, wc_lo, IN_CH,
                                       bcomb, hbuf, N_NODES, CPH);

    pool_kernel2<<<NG, 128, 0, stream>>>(hbuf, batch, pooled);

    head_kernel<<<1, 64, 0, stream>>>(pooled, W1, b1, W2, b2, W3, b3, out);
}

// Round 6
// 669.526 us; speedup vs baseline: 8.4952x; 1.0651x over previous
//
#include <hip/hip_runtime.h>
#include <hip/hip_bf16.h>
#include <math.h>

#define N_NODES 20000
#define N_EDGES 320000
#define IN_CH   128
#define HEADS   8
#define CPH     128
#define HCH     1024
#define NG      64
#define ETOT    (N_EDGES + N_NODES)

typedef __attribute__((ext_vector_type(8))) short s8v;
typedef __attribute__((ext_vector_type(4))) float f4v;
typedef __attribute__((ext_vector_type(4))) unsigned short u16x4;
typedef __attribute__((ext_vector_type(4))) int i4v;

// ---- fp32 -> bf16 split helpers (RNE) ----
__device__ __forceinline__ unsigned short bf16_rne(float f) {
    unsigned u = __float_as_uint(f);
    unsigned r = u + 0x7fffu + ((u >> 16) & 1u);
    return (unsigned short)(r >> 16);
}
__device__ __forceinline__ float bf16_to_f(unsigned short h) {
    return __uint_as_float((unsigned)h << 16);
}

// ---- zero deg ----
__global__ void init_kernel(int* __restrict__ deg) {
    int i = blockIdx.x * blockDim.x + threadIdx.x;
    if (i < N_NODES) deg[i] = 0;
}

// ---- fp32 -> (hi,lo) bf16 planes, float4-vectorized ----
__global__ void cvt_all(const float* __restrict__ x,  const float* __restrict__ Wl,
                        const float* __restrict__ Wr, const float* __restrict__ Wlin,
                        unsigned short* __restrict__ xhi,  unsigned short* __restrict__ xlo,
                        unsigned short* __restrict__ wlhi, unsigned short* __restrict__ wllo,
                        unsigned short* __restrict__ wrhi, unsigned short* __restrict__ wrlo,
                        unsigned short* __restrict__ wnhi, unsigned short* __restrict__ wnlo)
{
    const int NX = N_NODES * IN_CH, NW = HCH * IN_CH;
    const int TOT4 = (NX + 3 * NW) >> 2;
    for (int q = blockIdx.x * blockDim.x + threadIdx.x; q < TOT4;
         q += gridDim.x * blockDim.x) {
        int i = q << 2;
        const float* s; unsigned short *hi, *lo; int k;
        if (i < NX)               { s = x;    hi = xhi;  lo = xlo;  k = i; }
        else if (i < NX + NW)     { s = Wl;   hi = wlhi; lo = wllo; k = i - NX; }
        else if (i < NX + 2 * NW) { s = Wr;   hi = wrhi; lo = wrlo; k = i - NX - NW; }
        else                      { s = Wlin; hi = wnhi; lo = wnlo; k = i - NX - 2 * NW; }
        f4v f = *(const f4v*)&s[k];
        u16x4 h, l;
        #pragma unroll
        for (int e = 0; e < 4; ++e) {
            unsigned short hh = bf16_rne(f[e]);
            h[e] = hh;
            l[e] = bf16_rne(f[e] - bf16_to_f(hh));
        }
        *(u16x4*)&hi[k] = h;
        *(u16x4*)&lo[k] = l;
    }
}

// ---- Wcomb = Wlin @ Wres  (128x128), bcomb = blin + Wlin @ bias_conv ----
__global__ __launch_bounds__(128) void wcomb_kernel(
    const float* __restrict__ Wlin, const float* __restrict__ Wres,
    const float* __restrict__ bias_conv, const float* __restrict__ blin,
    unsigned short* __restrict__ wchi, unsigned short* __restrict__ wclo,
    float* __restrict__ bcomb)
{
    const int j = blockIdx.x;
    const int t = threadIdx.x;
    float s = 0.0f, pb = 0.0f;
    for (int m = 0; m < HCH; ++m) {
        float wl = Wlin[j * HCH + m];
        s  += wl * Wres[m * IN_CH + t];
        pb += wl * bias_conv[m];
    }
    unsigned short h = bf16_rne(s);
    wchi[j * IN_CH + t] = h;
    wclo[j * IN_CH + t] = bf16_rne(s - bf16_to_f(h));
    if (t == 0) bcomb[j] = blin[j] + pb;
}

// ---- merged projection GEMM: xl = x@Wl.T+bl, xr = x@Wr.T+br (by selects) ----
// Tile 128x128, 4 waves, split-bf16 MFMA; LDS-staged coalesced epilogue.
__global__ __launch_bounds__(256) void proj_gemm(
    const unsigned short* __restrict__ Ahi, const unsigned short* __restrict__ Alo,
    const unsigned short* __restrict__ WLhi, const unsigned short* __restrict__ WLlo,
    const unsigned short* __restrict__ WRhi, const unsigned short* __restrict__ WRlo,
    const float* __restrict__ bl, const float* __restrict__ br,
    float* __restrict__ xl, float* __restrict__ xr, int M)
{
    __shared__ float cst[128][130];
    const int t    = threadIdx.x;
    const int wave = t >> 6, lane = t & 63;
    const int wr = wave >> 1, wc = wave & 1;
    const int l15 = lane & 15, lg = lane >> 4;
    const int m0 = blockIdx.x * 128 + wr * 64;
    const int by = blockIdx.y;
    const int sel = by >> 3;
    const int col0 = (by & 7) * 128;
    const unsigned short* Whi = sel ? WRhi : WLhi;
    const unsigned short* Wlo = sel ? WRlo : WLlo;
    const float* bias = sel ? br : bl;
    float* C = sel ? xr : xl;
    const int koff = lg * 8;
    const int K = IN_CH;

    int rowA[4], colB[4];
    #pragma unroll
    for (int i = 0; i < 4; ++i) { int r = m0 + i * 16 + l15; rowA[i] = r < M ? r : M - 1; }
    #pragma unroll
    for (int j = 0; j < 4; ++j) colB[j] = col0 + wc * 64 + j * 16 + l15;

    float bj[4];
    #pragma unroll
    for (int j = 0; j < 4; ++j) bj[j] = bias[colB[j]];

    f4v acc[4][4];
    #pragma unroll
    for (int i = 0; i < 4; ++i)
        #pragma unroll
        for (int j = 0; j < 4; ++j) acc[i][j] = (f4v){0.f, 0.f, 0.f, 0.f};

    for (int k0 = 0; k0 < K; k0 += 32) {
        s8v ah[4], al[4], bh[4], blv[4];
        #pragma unroll
        for (int i = 0; i < 4; ++i) {
            size_t off = (size_t)rowA[i] * K + k0 + koff;
            ah[i] = *(const s8v*)&Ahi[off];
            al[i] = *(const s8v*)&Alo[off];
        }
        #pragma unroll
        for (int j = 0; j < 4; ++j) {
            size_t off = (size_t)colB[j] * K + k0 + koff;
            bh[j]  = *(const s8v*)&Whi[off];
            blv[j] = *(const s8v*)&Wlo[off];
        }
        #pragma unroll
        for (int i = 0; i < 4; ++i)
            #pragma unroll
            for (int j = 0; j < 4; ++j) {
                acc[i][j] = __builtin_amdgcn_mfma_f32_16x16x32_bf16(ah[i], bh[j],  acc[i][j], 0, 0, 0);
                acc[i][j] = __builtin_amdgcn_mfma_f32_16x16x32_bf16(ah[i], blv[j], acc[i][j], 0, 0, 0);
                acc[i][j] = __builtin_amdgcn_mfma_f32_16x16x32_bf16(al[i], bh[j],  acc[i][j], 0, 0, 0);
            }
    }

    // stage into LDS (+bias), then coalesced float4 stores
    #pragma unroll
    for (int i = 0; i < 4; ++i)
        #pragma unroll
        for (int r = 0; r < 4; ++r) {
            int lr = wr * 64 + i * 16 + lg * 4 + r;
            #pragma unroll
            for (int j = 0; j < 4; ++j)
                cst[lr][wc * 64 + j * 16 + l15] = acc[i][j][r] + bj[j];
        }
    __syncthreads();

    const int c4 = t & 31;           // float4 column
    const int r8 = t >> 5;           // row within group of 8
    #pragma unroll
    for (int it = 0; it < 16; ++it) {
        int lr = it * 8 + r8;
        int row = blockIdx.x * 128 + lr;
        if (row < M) {
            f4v v = *(const f4v*)&cst[lr][c4 * 4];
            *(f4v*)&C[(size_t)row * HCH + col0 + c4 * 4] = v;
        }
    }
}

// ---- fused final GEMM: C = ELU( A1@B1.T (K1) + A2@B2.T (K2) + bias ), NN=128 ----
__global__ __launch_bounds__(256) void mfma_gemm2(
    const unsigned short* __restrict__ A1hi, const unsigned short* __restrict__ A1lo,
    const unsigned short* __restrict__ B1hi, const unsigned short* __restrict__ B1lo, int K1,
    const unsigned short* __restrict__ A2hi, const unsigned short* __restrict__ A2lo,
    const unsigned short* __restrict__ B2hi, const unsigned short* __restrict__ B2lo, int K2,
    const float* __restrict__ bias, float* __restrict__ C, int M)
{
    __shared__ float cst[128][130];
    const int t    = threadIdx.x;
    const int wave = t >> 6, lane = t & 63;
    const int wr = wave >> 1, wc = wave & 1;
    const int l15 = lane & 15, lg = lane >> 4;
    const int m0 = blockIdx.x * 128 + wr * 64;
    const int n0 = wc * 64;
    const int koff = lg * 8;

    int rowA[4], colB[4];
    #pragma unroll
    for (int i = 0; i < 4; ++i) { int r = m0 + i * 16 + l15; rowA[i] = r < M ? r : M - 1; }
    #pragma unroll
    for (int j = 0; j < 4; ++j) colB[j] = n0 + j * 16 + l15;

    float bj[4];
    #pragma unroll
    for (int j = 0; j < 4; ++j) bj[j] = bias[colB[j]];

    f4v acc[4][4];
    #pragma unroll
    for (int i = 0; i < 4; ++i)
        #pragma unroll
        for (int j = 0; j < 4; ++j) acc[i][j] = (f4v){0.f, 0.f, 0.f, 0.f};

    for (int k0 = 0; k0 < K1; k0 += 32) {
        s8v ah[4], al[4], bh[4], blv[4];
        #pragma unroll
        for (int i = 0; i < 4; ++i) {
            size_t off = (size_t)rowA[i] * K1 + k0 + koff;
            ah[i] = *(const s8v*)&A1hi[off];
            al[i] = *(const s8v*)&A1lo[off];
        }
        #pragma unroll
        for (int j = 0; j < 4; ++j) {
            size_t off = (size_t)colB[j] * K1 + k0 + koff;
            bh[j]  = *(const s8v*)&B1hi[off];
            blv[j] = *(const s8v*)&B1lo[off];
        }
        #pragma unroll
        for (int i = 0; i < 4; ++i)
            #pragma unroll
            for (int j = 0; j < 4; ++j) {
                acc[i][j] = __builtin_amdgcn_mfma_f32_16x16x32_bf16(ah[i], bh[j],  acc[i][j], 0, 0, 0);
                acc[i][j] = __builtin_amdgcn_mfma_f32_16x16x32_bf16(ah[i], blv[j], acc[i][j], 0, 0, 0);
                acc[i][j] = __builtin_amdgcn_mfma_f32_16x16x32_bf16(al[i], bh[j],  acc[i][j], 0, 0, 0);
            }
    }
    for (int k0 = 0; k0 < K2; k0 += 32) {
        s8v ah[4], al[4], bh[4], blv[4];
        #pragma unroll
        for (int i = 0; i < 4; ++i) {
            size_t off = (size_t)rowA[i] * K2 + k0 + koff;
            ah[i] = *(const s8v*)&A2hi[off];
            al[i] = *(const s8v*)&A2lo[off];
        }
        #pragma unroll
        for (int j = 0; j < 4; ++j) {
            size_t off = (size_t)colB[j] * K2 + k0 + koff;
            bh[j]  = *(const s8v*)&B2hi[off];
            blv[j] = *(const s8v*)&B2lo[off];
        }
        #pragma unroll
        for (int i = 0; i < 4; ++i)
            #pragma unroll
            for (int j = 0; j < 4; ++j) {
                acc[i][j] = __builtin_amdgcn_mfma_f32_16x16x32_bf16(ah[i], bh[j],  acc[i][j], 0, 0, 0);
                acc[i][j] = __builtin_amdgcn_mfma_f32_16x16x32_bf16(ah[i], blv[j], acc[i][j], 0, 0, 0);
                acc[i][j] = __builtin_amdgcn_mfma_f32_16x16x32_bf16(al[i], bh[j],  acc[i][j], 0, 0, 0);
            }
    }

    #pragma unroll
    for (int i = 0; i < 4; ++i)
        #pragma unroll
        for (int r = 0; r < 4; ++r) {
            int lr = wr * 64 + i * 16 + lg * 4 + r;
            #pragma unroll
            for (int j = 0; j < 4; ++j) {
                float v = acc[i][j][r] + bj[j];
                v = v > 0.0f ? v : expm1f(v);   // ELU
                cst[lr][n0 + j * 16 + l15] = v;
            }
        }
    __syncthreads();

    const int c4 = t & 31;
    const int r8 = t >> 5;
    #pragma unroll
    for (int it = 0; it < 16; ++it) {
        int lr = it * 8 + r8;
        int row = blockIdx.x * 128 + lr;
        if (row < M) {
            f4v v = *(const f4v*)&cst[lr][c4 * 4];
            *(f4v*)&C[(size_t)row * CPH + c4 * 4] = v;
        }
    }
}

// ---- CSR build: histogram ----
__global__ void hist_kernel(const int* __restrict__ ei, int* __restrict__ deg) {
    for (int e = blockIdx.x * blockDim.x + threadIdx.x; e < ETOT;
         e += gridDim.x * blockDim.x) {
        int dst = (e < N_EDGES) ? ei[N_EDGES + e] : (e - N_EDGES);
        atomicAdd(&deg[dst], 1);
    }
}

// ---- CSR build: single-block scan, 4 elems/thread ----
__global__ __launch_bounds__(256) void scan_kernel(
    const int* __restrict__ deg, int* __restrict__ rowptr, int* __restrict__ wof)
{
    __shared__ int wsum[4];
    __shared__ int carry_s;
    const int t = threadIdx.x, wave = t >> 6, lane = t & 63;
    if (t == 0) { carry_s = 0; rowptr[0] = 0; }
    __syncthreads();
    for (int base = 0; base < N_NODES; base += 1024) {
        int idx = base + t * 4;
        int d[4], p[4];
        #pragma unroll
        for (int k = 0; k < 4; ++k)
            d[k] = (idx + k < N_NODES) ? deg[idx + k] : 0;
        p[0] = d[0]; p[1] = p[0] + d[1]; p[2] = p[1] + d[2]; p[3] = p[2] + d[3];
        int v = p[3];
        #pragma unroll
        for (int off = 1; off < 64; off <<= 1) {
            int u = __shfl_up(v, off, 64);
            if (lane >= off) v += u;
        }
        if (lane == 63) wsum[wave] = v;
        __syncthreads();
        int woff = carry_s;
        #pragma unroll
        for (int w = 0; w < 4; ++w) if (w < wave) woff += wsum[w];
        int tbase = woff + v - p[3];     // exclusive prefix for this thread
        #pragma unroll
        for (int k = 0; k < 4; ++k) {
            if (idx + k < N_NODES) {
                rowptr[idx + k + 1] = tbase + p[k];
                wof[idx + k] = tbase + p[k] - d[k];
            }
        }
        __syncthreads();
        if (t == 255) carry_s = woff + v;
        __syncthreads();
    }
}

// ---- CSR build: scatter edge src ids ----
__global__ void scatter_kernel(const int* __restrict__ ei, int* __restrict__ wof,
                               int* __restrict__ csr_src)
{
    for (int e = blockIdx.x * blockDim.x + threadIdx.x; e < ETOT;
         e += gridDim.x * blockDim.x) {
        int src, dst;
        if (e < N_EDGES) { src = ei[e]; dst = ei[N_EDGES + e]; }
        else             { src = dst = e - N_EDGES; }
        int p = atomicAdd(&wof[dst], 1);
        csr_src[p] = src;
    }
}

// ---- fused logits + online softmax + aggregation -> bf16 hi/lo planes ----
__global__ __launch_bounds__(256) void agg_fused(
    const float* __restrict__ xl, const float* __restrict__ xr,
    const float* __restrict__ att,
    const int* __restrict__ rowptr, const int* __restrict__ csr_src,
    unsigned short* __restrict__ agg_hi, unsigned short* __restrict__ agg_lo)
{
    const int dst = blockIdx.x;
    const int t = threadIdx.x;
    const int beg = rowptr[dst], end = rowptr[dst + 1];

    const f4v b = *(const f4v*)&xr[(size_t)dst * HCH + t * 4];
    const f4v w = *(const f4v*)&att[t * 4];

    float m = -__builtin_inff(), s = 0.0f;
    f4v acc = {0.f, 0.f, 0.f, 0.f};

    for (int j = beg; j < end; ++j) {
        const int src = csr_src[j];
        const f4v v = *(const f4v*)&xl[(size_t)src * HCH + t * 4];
        float e0 = v[0] + b[0]; e0 = e0 > 0.f ? e0 : 0.2f * e0;
        float e1 = v[1] + b[1]; e1 = e1 > 0.f ? e1 : 0.2f * e1;
        float e2 = v[2] + b[2]; e2 = e2 > 0.f ? e2 : 0.2f * e2;
        float e3 = v[3] + b[3]; e3 = e3 > 0.f ? e3 : 0.2f * e3;
        float p = e0 * w[0] + e1 * w[1] + e2 * w[2] + e3 * w[3];
        #pragma unroll
        for (int off = 16; off; off >>= 1) p += __shfl_xor(p, off, 32);

        if (p > m) {                      // new max: rescale old state
            float scale = __expf(m - p);  // first iter: exp(-inf)=0
            s = s * scale + 1.0f;
            acc = acc * scale + v;
            m = p;
        } else {                          // common case: no rescale
            float pw = __expf(p - m);
            s += pw;
            acc += v * pw;
        }
    }

    const float inv = 1.0f / (s + 1e-16f);
    f4v r = acc * inv;
    u16x4 hv, lv;
    #pragma unroll
    for (int e = 0; e < 4; ++e) {
        unsigned short h = bf16_rne(r[e]);
        hv[e] = h;
        lv[e] = bf16_rne(r[e] - bf16_to_f(h));
    }
    *(u16x4*)&agg_hi[(size_t)dst * HCH + t * 4] = hv;
    *(u16x4*)&agg_lo[(size_t)dst * HCH + t * 4] = lv;
}

// ---- segmented mean pool (batch is sorted) ----
__global__ __launch_bounds__(128) void pool_kernel2(
    const float* __restrict__ h, const int* __restrict__ batch,
    float* __restrict__ pooled)
{
    const int g = blockIdx.x;
    const int t = threadIdx.x;
    int lo = 0, hi = N_NODES;
    while (lo < hi) { int mid = (lo + hi) >> 1; if (batch[mid] <  g) lo = mid + 1; else hi = mid; }
    const int s0 = lo;
    hi = N_NODES;
    while (lo < hi) { int mid = (lo + hi) >> 1; if (batch[mid] <= g) lo = mid + 1; else hi = mid; }
    const int s1 = lo;

    float acc = 0.0f;
    for (int n = s0; n < s1; ++n) acc += h[(size_t)n * CPH + t];
    pooled[g * CPH + t] = acc / fmaxf((float)(s1 - s0), 1.0f);
}

// ---- MLP head: one thread per graph ----
__global__ __launch_bounds__(64) void head_kernel(
    const float* __restrict__ pooled,
    const float* __restrict__ W1, const float* __restrict__ b1,
    const float* __restrict__ W2, const float* __restrict__ b2,
    const float* __restrict__ W3, const float* __restrict__ b3,
    float* __restrict__ out)
{
    const int g = threadIdx.x;
    float y1[16];
    for (int j = 0; j < 16; ++j) {
        float s = b1[j];
        for (int k = 0; k < CPH; ++k) s += W1[j * CPH + k] * pooled[g * CPH + k];
        y1[j] = fmaxf(s, 0.0f);
    }
    float y2[32];
    for (int j = 0; j < 32; ++j) {
        float s = b2[j];
        for (int k = 0; k < 16; ++k) s += W2[j * 16 + k] * y1[k];
        y2[j] = fmaxf(s, 0.0f);
    }
    for (int u = 0; u < 5; ++u) {
        float s = b3[u];
        for (int k = 0; k < 32; ++k) s += W3[u * 32 + k] * y2[k];
        out[g * 5 + u] = s;
    }
}

extern "C" void kernel_launch(void* const* d_in, const int* in_sizes, int n_in,
                              void* d_out, int out_size, void* d_ws, size_t ws_size,
                              hipStream_t stream)
{
    const float* x         = (const float*)d_in[0];
    const int*   ei        = (const int*)  d_in[1];
    const int*   batch     = (const int*)  d_in[2];
    const float* Wl        = (const float*)d_in[3];
    const float* bl        = (const float*)d_in[4];
    const float* Wr        = (const float*)d_in[5];
    const float* br        = (const float*)d_in[6];
    const float* att       = (const float*)d_in[7];
    const float* Wres      = (const float*)d_in[8];
    const float* bias_conv = (const float*)d_in[9];
    const float* Wlin      = (const float*)d_in[10];
    const float* blin      = (const float*)d_in[11];
    const float* W1        = (const float*)d_in[12];
    const float* b1        = (const float*)d_in[13];
    const float* W2        = (const float*)d_in[14];
    const float* b2        = (const float*)d_in[15];
    const float* W3        = (const float*)d_in[16];
    const float* b3        = (const float*)d_in[17];
    float* out = (float*)d_out;

    // ---- workspace layout (~267.9 MB; ws is ~256 MiB+slack, R3-proven) ----
    float* xl     = (float*)d_ws;                               // 20.48M f
    float* xr     = xl + (size_t)N_NODES * HCH;                 // 20.48M f
    unsigned short* agg_hi = (unsigned short*)(xr + (size_t)N_NODES * HCH); // 20.48M u16
    unsigned short* agg_lo = agg_hi + (size_t)N_NODES * HCH;    // 20.48M u16
    float* hbuf   = (float*)(agg_lo + (size_t)N_NODES * HCH);   // 2.56M f
    float* pooled = hbuf + (size_t)N_NODES * CPH;               // 8192 f
    float* bcomb  = pooled + NG * CPH;                          // 128 f
    unsigned short* x_hi  = (unsigned short*)(bcomb + 128);     // 2.56M u16
    unsigned short* x_lo  = x_hi  + (size_t)N_NODES * IN_CH;    // 2.56M u16
    unsigned short* wl_hi = x_lo  + (size_t)N_NODES * IN_CH;    // 131072 u16 each
    unsigned short* wl_lo = wl_hi + HCH * IN_CH;
    unsigned short* wr_hi = wl_lo + HCH * IN_CH;
    unsigned short* wr_lo = wr_hi + HCH * IN_CH;
    unsigned short* wn_hi = wr_lo + HCH * IN_CH;
    unsigned short* wn_lo = wn_hi + CPH * HCH;
    unsigned short* wc_hi = wn_lo + CPH * HCH;                  // 16384 u16
    unsigned short* wc_lo = wc_hi + CPH * IN_CH;

    // CSR structures alias hbuf (dead before mfma_gemm2 writes hbuf)
    int* deg     = (int*)hbuf;                                  // N
    int* rowptr  = deg + N_NODES;                               // N+1
    int* wof     = rowptr + N_NODES + 1;                        // N
    int* csr_src = wof + N_NODES;                               // ETOT

    init_kernel<<<(N_NODES + 255) / 256, 256, 0, stream>>>(deg);

    cvt_all<<<768, 256, 0, stream>>>(x, Wl, Wr, Wlin,
                                     x_hi, x_lo, wl_hi, wl_lo,
                                     wr_hi, wr_lo, wn_hi, wn_lo);

    wcomb_kernel<<<CPH, 128, 0, stream>>>(Wlin, Wres, bias_conv, blin, wc_hi, wc_lo, bcomb);

    dim3 gp((N_NODES + 127) / 128, 16);
    proj_gemm<<<gp, 256, 0, stream>>>(x_hi, x_lo, wl_hi, wl_lo, wr_hi, wr_lo,
                                      bl, br, xl, xr, N_NODES);

    hist_kernel<<<1024, 256, 0, stream>>>(ei, deg);
    scan_kernel<<<1, 256, 0, stream>>>(deg, rowptr, wof);
    scatter_kernel<<<1024, 256, 0, stream>>>(ei, wof, csr_src);

    agg_fused<<<N_NODES, 256, 0, stream>>>(xl, xr, att, rowptr, csr_src, agg_hi, agg_lo);

    dim3 g2((N_NODES + 127) / 128, 1);
    mfma_gemm2<<<g2, 256, 0, stream>>>(agg_hi, agg_lo, wn_hi, wn_lo, HCH,
                                       x_hi, x_lo, wc_hi, wc_lo, IN_CH,
                                       bcomb, hbuf, N_NODES);

    pool_kernel2<<<NG, 128, 0, stream>>>(hbuf, batch, pooled);

    head_kernel<<<1, 64, 0, stream>>>(pooled, W1, b1, W2, b2, W3, b3, out);
}

// Round 7
// 536.738 us; speedup vs baseline: 10.5970x; 1.2474x over previous
//
#include <hip/hip_runtime.h>
#include <hip/hip_bf16.h>
#include <math.h>

#define N_NODES 20000
#define N_EDGES 320000
#define IN_CH   128
#define HEADS   8
#define CPH     128
#define HCH     1024
#define NG      64
#define ETOT    (N_EDGES + N_NODES)

typedef __attribute__((ext_vector_type(8))) short s8v;
typedef __attribute__((ext_vector_type(4))) float f4v;
typedef __attribute__((ext_vector_type(4))) unsigned short u16x4;

// ---- fp32 -> bf16 split helpers (RNE) ----
__device__ __forceinline__ unsigned short bf16_rne(float f) {
    unsigned u = __float_as_uint(f);
    unsigned r = u + 0x7fffu + ((u >> 16) & 1u);
    return (unsigned short)(r >> 16);
}
__device__ __forceinline__ float bf16_to_f(unsigned short h) {
    return __uint_as_float((unsigned)h << 16);
}

// ---- zero deg ----
__global__ void init_kernel(int* __restrict__ deg) {
    int i = blockIdx.x * blockDim.x + threadIdx.x;
    if (i < N_NODES) deg[i] = 0;
}

// ---- fp32 -> (hi,lo) bf16 planes + edge histogram (deg pre-zeroed) ----
__global__ void cvt_all(const float* __restrict__ x,  const float* __restrict__ Wl,
                        const float* __restrict__ Wr, const float* __restrict__ Wlin,
                        unsigned short* __restrict__ xhi,  unsigned short* __restrict__ xlo,
                        unsigned short* __restrict__ wlhi, unsigned short* __restrict__ wllo,
                        unsigned short* __restrict__ wrhi, unsigned short* __restrict__ wrlo,
                        unsigned short* __restrict__ wnhi, unsigned short* __restrict__ wnlo,
                        const int* __restrict__ ei, int* __restrict__ deg)
{
    const int NX = N_NODES * IN_CH, NW = HCH * IN_CH;
    const int TOT4 = (NX + 3 * NW) >> 2;
    for (int q = blockIdx.x * blockDim.x + threadIdx.x; q < TOT4;
         q += gridDim.x * blockDim.x) {
        int i = q << 2;
        const float* s; unsigned short *hi, *lo; int k;
        if (i < NX)               { s = x;    hi = xhi;  lo = xlo;  k = i; }
        else if (i < NX + NW)     { s = Wl;   hi = wlhi; lo = wllo; k = i - NX; }
        else if (i < NX + 2 * NW) { s = Wr;   hi = wrhi; lo = wrlo; k = i - NX - NW; }
        else                      { s = Wlin; hi = wnhi; lo = wnlo; k = i - NX - 2 * NW; }
        f4v f = *(const f4v*)&s[k];
        u16x4 h, l;
        #pragma unroll
        for (int e = 0; e < 4; ++e) {
            unsigned short hh = bf16_rne(f[e]);
            h[e] = hh;
            l[e] = bf16_rne(f[e] - bf16_to_f(hh));
        }
        *(u16x4*)&hi[k] = h;
        *(u16x4*)&lo[k] = l;
    }
    // edge histogram (fused; deg zeroed by init_kernel beforehand)
    for (int e = blockIdx.x * blockDim.x + threadIdx.x; e < ETOT;
         e += gridDim.x * blockDim.x) {
        int dst = (e < N_EDGES) ? ei[N_EDGES + e] : (e - N_EDGES);
        atomicAdd(&deg[dst], 1);
    }
}

// ---- Wcomb = Wlin @ Wres  (128x128), bcomb = blin + Wlin @ bias_conv ----
__global__ __launch_bounds__(128) void wcomb_kernel(
    const float* __restrict__ Wlin, const float* __restrict__ Wres,
    const float* __restrict__ bias_conv, const float* __restrict__ blin,
    unsigned short* __restrict__ wchi, unsigned short* __restrict__ wclo,
    float* __restrict__ bcomb)
{
    const int j = blockIdx.x;
    const int t = threadIdx.x;
    float s = 0.0f, pb = 0.0f;
    for (int m = 0; m < HCH; ++m) {
        float wl = Wlin[j * HCH + m];
        s  += wl * Wres[m * IN_CH + t];
        pb += wl * bias_conv[m];
    }
    unsigned short h = bf16_rne(s);
    wchi[j * IN_CH + t] = h;
    wclo[j * IN_CH + t] = bf16_rne(s - bf16_to_f(h));
    if (t == 0) bcomb[j] = blin[j] + pb;
}

// ---- merged projection GEMM: xl(bf16) = x@Wl.T+bl, xr(f32) = x@Wr.T+br ----
__global__ __launch_bounds__(256) void proj_gemm(
    const unsigned short* __restrict__ Ahi, const unsigned short* __restrict__ Alo,
    const unsigned short* __restrict__ WLhi, const unsigned short* __restrict__ WLlo,
    const unsigned short* __restrict__ WRhi, const unsigned short* __restrict__ WRlo,
    const float* __restrict__ bl, const float* __restrict__ br,
    unsigned short* __restrict__ xl_h, float* __restrict__ xr, int M)
{
    __shared__ float cst[128][130];
    const int t    = threadIdx.x;
    const int wave = t >> 6, lane = t & 63;
    const int wr = wave >> 1, wc = wave & 1;
    const int l15 = lane & 15, lg = lane >> 4;
    const int m0 = blockIdx.x * 128 + wr * 64;
    const int by = blockIdx.y;
    const int sel = by >> 3;
    const int col0 = (by & 7) * 128;
    const unsigned short* Whi = sel ? WRhi : WLhi;
    const unsigned short* Wlo = sel ? WRlo : WLlo;
    const float* bias = sel ? br : bl;
    const int koff = lg * 8;
    const int K = IN_CH;

    int rowA[4], colB[4];
    #pragma unroll
    for (int i = 0; i < 4; ++i) { int r = m0 + i * 16 + l15; rowA[i] = r < M ? r : M - 1; }
    #pragma unroll
    for (int j = 0; j < 4; ++j) colB[j] = col0 + wc * 64 + j * 16 + l15;

    float bj[4];
    #pragma unroll
    for (int j = 0; j < 4; ++j) bj[j] = bias[colB[j]];

    f4v acc[4][4];
    #pragma unroll
    for (int i = 0; i < 4; ++i)
        #pragma unroll
        for (int j = 0; j < 4; ++j) acc[i][j] = (f4v){0.f, 0.f, 0.f, 0.f};

    for (int k0 = 0; k0 < K; k0 += 32) {
        s8v ah[4], al[4], bh[4], blv[4];
        #pragma unroll
        for (int i = 0; i < 4; ++i) {
            size_t off = (size_t)rowA[i] * K + k0 + koff;
            ah[i] = *(const s8v*)&Ahi[off];
            al[i] = *(const s8v*)&Alo[off];
        }
        #pragma unroll
        for (int j = 0; j < 4; ++j) {
            size_t off = (size_t)colB[j] * K + k0 + koff;
            bh[j]  = *(const s8v*)&Whi[off];
            blv[j] = *(const s8v*)&Wlo[off];
        }
        #pragma unroll
        for (int i = 0; i < 4; ++i)
            #pragma unroll
            for (int j = 0; j < 4; ++j) {
                acc[i][j] = __builtin_amdgcn_mfma_f32_16x16x32_bf16(ah[i], bh[j],  acc[i][j], 0, 0, 0);
                acc[i][j] = __builtin_amdgcn_mfma_f32_16x16x32_bf16(ah[i], blv[j], acc[i][j], 0, 0, 0);
                acc[i][j] = __builtin_amdgcn_mfma_f32_16x16x32_bf16(al[i], bh[j],  acc[i][j], 0, 0, 0);
            }
    }

    #pragma unroll
    for (int i = 0; i < 4; ++i)
        #pragma unroll
        for (int r = 0; r < 4; ++r) {
            int lr = wr * 64 + i * 16 + lg * 4 + r;
            #pragma unroll
            for (int j = 0; j < 4; ++j)
                cst[lr][wc * 64 + j * 16 + l15] = acc[i][j][r] + bj[j];
        }
    __syncthreads();

    const int c4 = t & 31;           // float4 column within 128
    const int r8 = t >> 5;
    #pragma unroll
    for (int it = 0; it < 16; ++it) {
        int lr = it * 8 + r8;
        int row = blockIdx.x * 128 + lr;
        if (row >= M) continue;
        f4v v = *(const f4v*)&cst[lr][c4 * 4];
        if (sel) {
            *(f4v*)&xr[(size_t)row * HCH + col0 + c4 * 4] = v;
        } else {
            u16x4 hv;
            #pragma unroll
            for (int e = 0; e < 4; ++e) hv[e] = bf16_rne(v[e]);
            *(u16x4*)&xl_h[(size_t)row * HCH + col0 + c4 * 4] = hv;
        }
    }
}

// ---- fused final GEMM: C = ELU( A1(bf16)@B1.T (K1) + A2(hi/lo)@B2.T (K2) + bias ) ----
__global__ __launch_bounds__(256) void mfma_gemm2(
    const unsigned short* __restrict__ A1h,
    const unsigned short* __restrict__ B1hi, const unsigned short* __restrict__ B1lo, int K1,
    const unsigned short* __restrict__ A2hi, const unsigned short* __restrict__ A2lo,
    const unsigned short* __restrict__ B2hi, const unsigned short* __restrict__ B2lo, int K2,
    const float* __restrict__ bias, float* __restrict__ C, int M)
{
    __shared__ float cst[128][130];
    const int t    = threadIdx.x;
    const int wave = t >> 6, lane = t & 63;
    const int wr = wave >> 1, wc = wave & 1;
    const int l15 = lane & 15, lg = lane >> 4;
    const int m0 = blockIdx.x * 128 + wr * 64;
    const int n0 = wc * 64;
    const int koff = lg * 8;

    int rowA[4], colB[4];
    #pragma unroll
    for (int i = 0; i < 4; ++i) { int r = m0 + i * 16 + l15; rowA[i] = r < M ? r : M - 1; }
    #pragma unroll
    for (int j = 0; j < 4; ++j) colB[j] = n0 + j * 16 + l15;

    float bj[4];
    #pragma unroll
    for (int j = 0; j < 4; ++j) bj[j] = bias[colB[j]];

    f4v acc[4][4];
    #pragma unroll
    for (int i = 0; i < 4; ++i)
        #pragma unroll
        for (int j = 0; j < 4; ++j) acc[i][j] = (f4v){0.f, 0.f, 0.f, 0.f};

    for (int k0 = 0; k0 < K1; k0 += 32) {
        s8v ah[4], bh[4], blv[4];
        #pragma unroll
        for (int i = 0; i < 4; ++i)
            ah[i] = *(const s8v*)&A1h[(size_t)rowA[i] * K1 + k0 + koff];
        #pragma unroll
        for (int j = 0; j < 4; ++j) {
            size_t off = (size_t)colB[j] * K1 + k0 + koff;
            bh[j]  = *(const s8v*)&B1hi[off];
            blv[j] = *(const s8v*)&B1lo[off];
        }
        #pragma unroll
        for (int i = 0; i < 4; ++i)
            #pragma unroll
            for (int j = 0; j < 4; ++j) {
                acc[i][j] = __builtin_amdgcn_mfma_f32_16x16x32_bf16(ah[i], bh[j],  acc[i][j], 0, 0, 0);
                acc[i][j] = __builtin_amdgcn_mfma_f32_16x16x32_bf16(ah[i], blv[j], acc[i][j], 0, 0, 0);
            }
    }
    for (int k0 = 0; k0 < K2; k0 += 32) {
        s8v ah[4], al[4], bh[4], blv[4];
        #pragma unroll
        for (int i = 0; i < 4; ++i) {
            size_t off = (size_t)rowA[i] * K2 + k0 + koff;
            ah[i] = *(const s8v*)&A2hi[off];
            al[i] = *(const s8v*)&A2lo[off];
        }
        #pragma unroll
        for (int j = 0; j < 4; ++j) {
            size_t off = (size_t)colB[j] * K2 + k0 + koff;
            bh[j]  = *(const s8v*)&B2hi[off];
            blv[j] = *(const s8v*)&B2lo[off];
        }
        #pragma unroll
        for (int i = 0; i < 4; ++i)
            #pragma unroll
            for (int j = 0; j < 4; ++j) {
                acc[i][j] = __builtin_amdgcn_mfma_f32_16x16x32_bf16(ah[i], bh[j],  acc[i][j], 0, 0, 0);
                acc[i][j] = __builtin_amdgcn_mfma_f32_16x16x32_bf16(ah[i], blv[j], acc[i][j], 0, 0, 0);
                acc[i][j] = __builtin_amdgcn_mfma_f32_16x16x32_bf16(al[i], bh[j],  acc[i][j], 0, 0, 0);
            }
    }

    #pragma unroll
    for (int i = 0; i < 4; ++i)
        #pragma unroll
        for (int r = 0; r < 4; ++r) {
            int lr = wr * 64 + i * 16 + lg * 4 + r;
            #pragma unroll
            for (int j = 0; j < 4; ++j) {
                float v = acc[i][j][r] + bj[j];
                v = v > 0.0f ? v : expm1f(v);   // ELU
                cst[lr][n0 + j * 16 + l15] = v;
            }
        }
    __syncthreads();

    const int c4 = t & 31;
    const int r8 = t >> 5;
    #pragma unroll
    for (int it = 0; it < 16; ++it) {
        int lr = it * 8 + r8;
        int row = blockIdx.x * 128 + lr;
        if (row < M) {
            f4v v = *(const f4v*)&cst[lr][c4 * 4];
            *(f4v*)&C[(size_t)row * CPH + c4 * 4] = v;
        }
    }
}

// ---- CSR build: single-block scan, 4 elems/thread ----
__global__ __launch_bounds__(256) void scan_kernel(
    const int* __restrict__ deg, int* __restrict__ rowptr, int* __restrict__ wof)
{
    __shared__ int wsum[4];
    __shared__ int carry_s;
    const int t = threadIdx.x, wave = t >> 6, lane = t & 63;
    if (t == 0) { carry_s = 0; rowptr[0] = 0; }
    __syncthreads();
    for (int base = 0; base < N_NODES; base += 1024) {
        int idx = base + t * 4;
        int d[4], p[4];
        #pragma unroll
        for (int k = 0; k < 4; ++k)
            d[k] = (idx + k < N_NODES) ? deg[idx + k] : 0;
        p[0] = d[0]; p[1] = p[0] + d[1]; p[2] = p[1] + d[2]; p[3] = p[2] + d[3];
        int v = p[3];
        #pragma unroll
        for (int off = 1; off < 64; off <<= 1) {
            int u = __shfl_up(v, off, 64);
            if (lane >= off) v += u;
        }
        if (lane == 63) wsum[wave] = v;
        __syncthreads();
        int woff = carry_s;
        #pragma unroll
        for (int w = 0; w < 4; ++w) if (w < wave) woff += wsum[w];
        int tbase = woff + v - p[3];
        #pragma unroll
        for (int k = 0; k < 4; ++k) {
            if (idx + k < N_NODES) {
                rowptr[idx + k + 1] = tbase + p[k];
                wof[idx + k] = tbase + p[k] - d[k];
            }
        }
        __syncthreads();
        if (t == 255) carry_s = woff + v;
        __syncthreads();
    }
}

// ---- CSR build: scatter edge src ids ----
__global__ void scatter_kernel(const int* __restrict__ ei, int* __restrict__ wof,
                               int* __restrict__ csr_src)
{
    for (int e = blockIdx.x * blockDim.x + threadIdx.x; e < ETOT;
         e += gridDim.x * blockDim.x) {
        int src, dst;
        if (e < N_EDGES) { src = ei[e]; dst = ei[N_EDGES + e]; }
        else             { src = dst = e - N_EDGES; }
        int p = atomicAdd(&wof[dst], 1);
        csr_src[p] = src;
    }
}

// ---- fused logits + online softmax + aggregation (bf16 gather) ----
__global__ __launch_bounds__(256) void agg_fused(
    const unsigned short* __restrict__ xl_h, const float* __restrict__ xr,
    const float* __restrict__ att,
    const int* __restrict__ rowptr, const int* __restrict__ csr_src,
    unsigned short* __restrict__ agg_h)
{
    const int dst = blockIdx.x;
    const int t = threadIdx.x;
    const int beg = rowptr[dst], end = rowptr[dst + 1];

    const f4v b = *(const f4v*)&xr[(size_t)dst * HCH + t * 4];
    const f4v w = *(const f4v*)&att[t * 4];

    float m = -__builtin_inff(), s = 0.0f;
    f4v acc = {0.f, 0.f, 0.f, 0.f};

    for (int j = beg; j < end; ++j) {
        const int src = csr_src[j];
        const u16x4 vh = *(const u16x4*)&xl_h[(size_t)src * HCH + t * 4];
        f4v v;
        #pragma unroll
        for (int e = 0; e < 4; ++e) v[e] = bf16_to_f(vh[e]);
        float e0 = v[0] + b[0]; e0 = e0 > 0.f ? e0 : 0.2f * e0;
        float e1 = v[1] + b[1]; e1 = e1 > 0.f ? e1 : 0.2f * e1;
        float e2 = v[2] + b[2]; e2 = e2 > 0.f ? e2 : 0.2f * e2;
        float e3 = v[3] + b[3]; e3 = e3 > 0.f ? e3 : 0.2f * e3;
        float p = e0 * w[0] + e1 * w[1] + e2 * w[2] + e3 * w[3];
        #pragma unroll
        for (int off = 16; off; off >>= 1) p += __shfl_xor(p, off, 32);

        if (p > m) {
            float scale = __expf(m - p);   // first iter: exp(-inf)=0
            s = s * scale + 1.0f;
            acc = acc * scale + v;
            m = p;
        } else {
            float pw = __expf(p - m);
            s += pw;
            acc += v * pw;
        }
    }

    const float inv = 1.0f / (s + 1e-16f);
    f4v r = acc * inv;
    u16x4 hv;
    #pragma unroll
    for (int e = 0; e < 4; ++e) hv[e] = bf16_rne(r[e]);
    *(u16x4*)&agg_h[(size_t)dst * HCH + t * 4] = hv;
}

// ---- segmented mean pool (batch is sorted) ----
__global__ __launch_bounds__(128) void pool_kernel2(
    const float* __restrict__ h, const int* __restrict__ batch,
    float* __restrict__ pooled)
{
    const int g = blockIdx.x;
    const int t = threadIdx.x;
    int lo = 0, hi = N_NODES;
    while (lo < hi) { int mid = (lo + hi) >> 1; if (batch[mid] <  g) lo = mid + 1; else hi = mid; }
    const int s0 = lo;
    hi = N_NODES;
    while (lo < hi) { int mid = (lo + hi) >> 1; if (batch[mid] <= g) lo = mid + 1; else hi = mid; }
    const int s1 = lo;

    float acc = 0.0f;
    for (int n = s0; n < s1; ++n) acc += h[(size_t)n * CPH + t];
    pooled[g * CPH + t] = acc / fmaxf((float)(s1 - s0), 1.0f);
}

// ---- MLP head: one thread per graph ----
__global__ __launch_bounds__(64) void head_kernel(
    const float* __restrict__ pooled,
    const float* __restrict__ W1, const float* __restrict__ b1,
    const float* __restrict__ W2, const float* __restrict__ b2,
    const float* __restrict__ W3, const float* __restrict__ b3,
    float* __restrict__ out)
{
    const int g = threadIdx.x;
    float y1[16];
    for (int j = 0; j < 16; ++j) {
        float s = b1[j];
        for (int k = 0; k < CPH; ++k) s += W1[j * CPH + k] * pooled[g * CPH + k];
        y1[j] = fmaxf(s, 0.0f);
    }
    float y2[32];
    for (int j = 0; j < 32; ++j) {
        float s = b2[j];
        for (int k = 0; k < 16; ++k) s += W2[j * 16 + k] * y1[k];
        y2[j] = fmaxf(s, 0.0f);
    }
    for (int u = 0; u < 5; ++u) {
        float s = b3[u];
        for (int k = 0; k < 32; ++k) s += W3[u * 32 + k] * y2[k];
        out[g * 5 + u] = s;
    }
}

extern "C" void kernel_launch(void* const* d_in, const int* in_sizes, int n_in,
                              void* d_out, int out_size, void* d_ws, size_t ws_size,
                              hipStream_t stream)
{
    const float* x         = (const float*)d_in[0];
    const int*   ei        = (const int*)  d_in[1];
    const int*   batch     = (const int*)  d_in[2];
    const float* Wl        = (const float*)d_in[3];
    const float* bl        = (const float*)d_in[4];
    const float* Wr        = (const float*)d_in[5];
    const float* br        = (const float*)d_in[6];
    const float* att       = (const float*)d_in[7];
    const float* Wres      = (const float*)d_in[8];
    const float* bias_conv = (const float*)d_in[9];
    const float* Wlin      = (const float*)d_in[10];
    const float* blin      = (const float*)d_in[11];
    const float* W1        = (const float*)d_in[12];
    const float* b1        = (const float*)d_in[13];
    const float* W2        = (const float*)d_in[14];
    const float* b2        = (const float*)d_in[15];
    const float* W3        = (const float*)d_in[16];
    const float* b3        = (const float*)d_in[17];
    float* out = (float*)d_out;

    // ---- workspace layout (~185 MB, well under the ~256 MiB+slack limit) ----
    unsigned short* xl_h = (unsigned short*)d_ws;               // N*HCH u16  41 MB
    float* xr     = (float*)(xl_h + (size_t)N_NODES * HCH);     // N*HCH f32  82 MB
    unsigned short* agg_h = (unsigned short*)(xr + (size_t)N_NODES * HCH); // N*HCH u16 41 MB
    float* hbuf   = (float*)(agg_h + (size_t)N_NODES * HCH);    // N*CPH f32  10.2 MB
    float* pooled = hbuf + (size_t)N_NODES * CPH;
    float* bcomb  = pooled + NG * CPH;
    unsigned short* x_hi  = (unsigned short*)(bcomb + 128);     // N*IN u16
    unsigned short* x_lo  = x_hi  + (size_t)N_NODES * IN_CH;
    unsigned short* wl_hi = x_lo  + (size_t)N_NODES * IN_CH;
    unsigned short* wl_lo = wl_hi + HCH * IN_CH;
    unsigned short* wr_hi = wl_lo + HCH * IN_CH;
    unsigned short* wr_lo = wr_hi + HCH * IN_CH;
    unsigned short* wn_hi = wr_lo + HCH * IN_CH;
    unsigned short* wn_lo = wn_hi + CPH * HCH;
    unsigned short* wc_hi = wn_lo + CPH * HCH;
    unsigned short* wc_lo = wc_hi + CPH * IN_CH;

    // CSR structures alias hbuf (dead before mfma_gemm2 writes hbuf)
    int* deg     = (int*)hbuf;
    int* rowptr  = deg + N_NODES;
    int* wof     = rowptr + N_NODES + 1;
    int* csr_src = wof + N_NODES;

    init_kernel<<<(N_NODES + 255) / 256, 256, 0, stream>>>(deg);

    cvt_all<<<768, 256, 0, stream>>>(x, Wl, Wr, Wlin,
                                     x_hi, x_lo, wl_hi, wl_lo,
                                     wr_hi, wr_lo, wn_hi, wn_lo,
                                     ei, deg);

    wcomb_kernel<<<CPH, 128, 0, stream>>>(Wlin, Wres, bias_conv, blin, wc_hi, wc_lo, bcomb);

    dim3 gp((N_NODES + 127) / 128, 16);
    proj_gemm<<<gp, 256, 0, stream>>>(x_hi, x_lo, wl_hi, wl_lo, wr_hi, wr_lo,
                                      bl, br, xl_h, xr, N_NODES);

    scan_kernel<<<1, 256, 0, stream>>>(deg, rowptr, wof);
    scatter_kernel<<<1024, 256, 0, stream>>>(ei, wof, csr_src);

    agg_fused<<<N_NODES, 256, 0, stream>>>(xl_h, xr, att, rowptr, csr_src, agg_h);

    dim3 g2((N_NODES + 127) / 128, 1);
    mfma_gemm2<<<g2, 256, 0, stream>>>(agg_h, wn_hi, wn_lo, HCH,
                                       x_hi, x_lo, wc_hi, wc_lo, IN_CH,
                                       bcomb, hbuf, N_NODES);

    pool_kernel2<<<NG, 128, 0, stream>>>(hbuf, batch, pooled);

    head_kernel<<<1, 64, 0, stream>>>(pooled, W1, b1, W2, b2, W3, b3, out);
}

// Round 8
// 455.471 us; speedup vs baseline: 12.4877x; 1.1784x over previous
//
#include <hip/hip_runtime.h>
#include <hip/hip_bf16.h>
#include <math.h>

#define N_NODES 20000
#define N_EDGES 320000
#define IN_CH   128
#define HEADS   8
#define CPH     128
#define HCH     1024
#define NG      64
#define ETOT    (N_EDGES + N_NODES)
#define NCVT    768

typedef __attribute__((ext_vector_type(8))) short s8v;
typedef __attribute__((ext_vector_type(4))) float f4v;
typedef __attribute__((ext_vector_type(4))) unsigned short u16x4;

// ---- fp32 -> bf16 split helpers (RNE) ----
__device__ __forceinline__ unsigned short bf16_rne(float f) {
    unsigned u = __float_as_uint(f);
    unsigned r = u + 0x7fffu + ((u >> 16) & 1u);
    return (unsigned short)(r >> 16);
}
__device__ __forceinline__ float bf16_to_f(unsigned short h) {
    return __uint_as_float((unsigned)h << 16);
}

// ---- zero deg + pooled ----
__global__ void init_kernel(int* __restrict__ deg, float* __restrict__ pooled) {
    int i = blockIdx.x * blockDim.x + threadIdx.x;
    if (i < N_NODES) deg[i] = 0;
    if (i < NG * CPH) pooled[i] = 0.0f;
}

// ---- fp32 -> (hi,lo) bf16 planes + edge histogram + wcomb (merged) ----
__global__ void cvt_all(const float* __restrict__ x,  const float* __restrict__ Wl,
                        const float* __restrict__ Wr, const float* __restrict__ Wlin,
                        unsigned short* __restrict__ xhi,  unsigned short* __restrict__ xlo,
                        unsigned short* __restrict__ wlhi, unsigned short* __restrict__ wllo,
                        unsigned short* __restrict__ wrhi, unsigned short* __restrict__ wrlo,
                        unsigned short* __restrict__ wnhi, unsigned short* __restrict__ wnlo,
                        const int* __restrict__ ei, int* __restrict__ deg,
                        const float* __restrict__ Wres, const float* __restrict__ bias_conv,
                        const float* __restrict__ blin,
                        unsigned short* __restrict__ wchi, unsigned short* __restrict__ wclo,
                        float* __restrict__ bcomb)
{
    const int t = threadIdx.x;
    if (blockIdx.x < NCVT) {
        const int NX = N_NODES * IN_CH, NW = HCH * IN_CH;
        const int TOT4 = (NX + 3 * NW) >> 2;
        const int stride = NCVT * 256;
        for (int q = blockIdx.x * 256 + t; q < TOT4; q += stride) {
            int i = q << 2;
            const float* s; unsigned short *hi, *lo; int k;
            if (i < NX)               { s = x;    hi = xhi;  lo = xlo;  k = i; }
            else if (i < NX + NW)     { s = Wl;   hi = wlhi; lo = wllo; k = i - NX; }
            else if (i < NX + 2 * NW) { s = Wr;   hi = wrhi; lo = wrlo; k = i - NX - NW; }
            else                      { s = Wlin; hi = wnhi; lo = wnlo; k = i - NX - 2 * NW; }
            f4v f = *(const f4v*)&s[k];
            u16x4 h, l;
            #pragma unroll
            for (int e = 0; e < 4; ++e) {
                unsigned short hh = bf16_rne(f[e]);
                h[e] = hh;
                l[e] = bf16_rne(f[e] - bf16_to_f(hh));
            }
            *(u16x4*)&hi[k] = h;
            *(u16x4*)&lo[k] = l;
        }
        for (int e = blockIdx.x * 256 + t; e < ETOT; e += stride) {
            int dst = (e < N_EDGES) ? ei[N_EDGES + e] : (e - N_EDGES);
            atomicAdd(&deg[dst], 1);
        }
    } else if (t < 128) {
        // Wcomb = Wlin @ Wres, bcomb = blin + Wlin @ bias_conv
        const int j = blockIdx.x - NCVT;    // 0..127
        float s = 0.0f, pb = 0.0f;
        for (int m = 0; m < HCH; ++m) {
            float wl = Wlin[j * HCH + m];
            s  += wl * Wres[m * IN_CH + t];
            pb += wl * bias_conv[m];
        }
        unsigned short h = bf16_rne(s);
        wchi[j * IN_CH + t] = h;
        wclo[j * IN_CH + t] = bf16_rne(s - bf16_to_f(h));
        if (t == 0) bcomb[j] = blin[j] + pb;
    }
}

// ---- merged projection GEMM: xl(bf16) = x@Wl.T+bl, xr(bf16) = x@Wr.T+br ----
__global__ __launch_bounds__(256) void proj_gemm(
    const unsigned short* __restrict__ Ahi, const unsigned short* __restrict__ Alo,
    const unsigned short* __restrict__ WLhi, const unsigned short* __restrict__ WLlo,
    const unsigned short* __restrict__ WRhi, const unsigned short* __restrict__ WRlo,
    const float* __restrict__ bl, const float* __restrict__ br,
    unsigned short* __restrict__ xl_h, unsigned short* __restrict__ xr_h, int M)
{
    __shared__ float cst[128][130];
    const int t    = threadIdx.x;
    const int wave = t >> 6, lane = t & 63;
    const int wr = wave >> 1, wc = wave & 1;
    const int l15 = lane & 15, lg = lane >> 4;
    const int m0 = blockIdx.x * 128 + wr * 64;
    const int by = blockIdx.y;
    const int sel = by >> 3;
    const int col0 = (by & 7) * 128;
    const unsigned short* Whi = sel ? WRhi : WLhi;
    const unsigned short* Wlo = sel ? WRlo : WLlo;
    const float* bias = sel ? br : bl;
    unsigned short* C = sel ? xr_h : xl_h;
    const int koff = lg * 8;
    const int K = IN_CH;

    int rowA[4], colB[4];
    #pragma unroll
    for (int i = 0; i < 4; ++i) { int r = m0 + i * 16 + l15; rowA[i] = r < M ? r : M - 1; }
    #pragma unroll
    for (int j = 0; j < 4; ++j) colB[j] = col0 + wc * 64 + j * 16 + l15;

    float bj[4];
    #pragma unroll
    for (int j = 0; j < 4; ++j) bj[j] = bias[colB[j]];

    f4v acc[4][4];
    #pragma unroll
    for (int i = 0; i < 4; ++i)
        #pragma unroll
        for (int j = 0; j < 4; ++j) acc[i][j] = (f4v){0.f, 0.f, 0.f, 0.f};

    for (int k0 = 0; k0 < K; k0 += 32) {
        s8v ah[4], al[4], bh[4], blv[4];
        #pragma unroll
        for (int i = 0; i < 4; ++i) {
            size_t off = (size_t)rowA[i] * K + k0 + koff;
            ah[i] = *(const s8v*)&Ahi[off];
            al[i] = *(const s8v*)&Alo[off];
        }
        #pragma unroll
        for (int j = 0; j < 4; ++j) {
            size_t off = (size_t)colB[j] * K + k0 + koff;
            bh[j]  = *(const s8v*)&Whi[off];
            blv[j] = *(const s8v*)&Wlo[off];
        }
        #pragma unroll
        for (int i = 0; i < 4; ++i)
            #pragma unroll
            for (int j = 0; j < 4; ++j) {
                acc[i][j] = __builtin_amdgcn_mfma_f32_16x16x32_bf16(ah[i], bh[j],  acc[i][j], 0, 0, 0);
                acc[i][j] = __builtin_amdgcn_mfma_f32_16x16x32_bf16(ah[i], blv[j], acc[i][j], 0, 0, 0);
                acc[i][j] = __builtin_amdgcn_mfma_f32_16x16x32_bf16(al[i], bh[j],  acc[i][j], 0, 0, 0);
            }
    }

    #pragma unroll
    for (int i = 0; i < 4; ++i)
        #pragma unroll
        for (int r = 0; r < 4; ++r) {
            int lr = wr * 64 + i * 16 + lg * 4 + r;
            #pragma unroll
            for (int j = 0; j < 4; ++j)
                cst[lr][wc * 64 + j * 16 + l15] = acc[i][j][r] + bj[j];
        }
    __syncthreads();

    const int c4 = t & 31;
    const int r8 = t >> 5;
    #pragma unroll
    for (int it = 0; it < 16; ++it) {
        int lr = it * 8 + r8;
        int row = blockIdx.x * 128 + lr;
        if (row >= M) continue;
        f4v v = *(const f4v*)&cst[lr][c4 * 4];
        u16x4 hv;
        #pragma unroll
        for (int e = 0; e < 4; ++e) hv[e] = bf16_rne(v[e]);
        *(u16x4*)&C[(size_t)row * HCH + col0 + c4 * 4] = hv;
    }
}

// ---- final GEMM + ELU + fused per-graph pooling (batch sorted) ----
__global__ __launch_bounds__(256) void mfma_gemm2(
    const unsigned short* __restrict__ A1h,
    const unsigned short* __restrict__ B1hi, const unsigned short* __restrict__ B1lo, int K1,
    const unsigned short* __restrict__ A2hi, const unsigned short* __restrict__ A2lo,
    const unsigned short* __restrict__ B2hi, const unsigned short* __restrict__ B2lo, int K2,
    const float* __restrict__ bias, const int* __restrict__ batch,
    float* __restrict__ pooled, int M)
{
    __shared__ float cst[128][130];
    __shared__ int batch_s[128];
    const int t    = threadIdx.x;
    const int wave = t >> 6, lane = t & 63;
    const int wr = wave >> 1, wc = wave & 1;
    const int l15 = lane & 15, lg = lane >> 4;
    const int m0 = blockIdx.x * 128 + wr * 64;
    const int n0 = wc * 64;
    const int koff = lg * 8;

    if (t < 128) {
        int row = blockIdx.x * 128 + t;
        batch_s[t] = (row < M) ? batch[row] : -1;
    }

    int rowA[4], colB[4];
    #pragma unroll
    for (int i = 0; i < 4; ++i) { int r = m0 + i * 16 + l15; rowA[i] = r < M ? r : M - 1; }
    #pragma unroll
    for (int j = 0; j < 4; ++j) colB[j] = n0 + j * 16 + l15;

    float bj[4];
    #pragma unroll
    for (int j = 0; j < 4; ++j) bj[j] = bias[colB[j]];

    f4v acc[4][4];
    #pragma unroll
    for (int i = 0; i < 4; ++i)
        #pragma unroll
        for (int j = 0; j < 4; ++j) acc[i][j] = (f4v){0.f, 0.f, 0.f, 0.f};

    for (int k0 = 0; k0 < K1; k0 += 32) {
        s8v ah[4], bh[4], blv[4];
        #pragma unroll
        for (int i = 0; i < 4; ++i)
            ah[i] = *(const s8v*)&A1h[(size_t)rowA[i] * K1 + k0 + koff];
        #pragma unroll
        for (int j = 0; j < 4; ++j) {
            size_t off = (size_t)colB[j] * K1 + k0 + koff;
            bh[j]  = *(const s8v*)&B1hi[off];
            blv[j] = *(const s8v*)&B1lo[off];
        }
        #pragma unroll
        for (int i = 0; i < 4; ++i)
            #pragma unroll
            for (int j = 0; j < 4; ++j) {
                acc[i][j] = __builtin_amdgcn_mfma_f32_16x16x32_bf16(ah[i], bh[j],  acc[i][j], 0, 0, 0);
                acc[i][j] = __builtin_amdgcn_mfma_f32_16x16x32_bf16(ah[i], blv[j], acc[i][j], 0, 0, 0);
            }
    }
    for (int k0 = 0; k0 < K2; k0 += 32) {
        s8v ah[4], al[4], bh[4], blv[4];
        #pragma unroll
        for (int i = 0; i < 4; ++i) {
            size_t off = (size_t)rowA[i] * K2 + k0 + koff;
            ah[i] = *(const s8v*)&A2hi[off];
            al[i] = *(const s8v*)&A2lo[off];
        }
        #pragma unroll
        for (int j = 0; j < 4; ++j) {
            size_t off = (size_t)colB[j] * K2 + k0 + koff;
            bh[j]  = *(const s8v*)&B2hi[off];
            blv[j] = *(const s8v*)&B2lo[off];
        }
        #pragma unroll
        for (int i = 0; i < 4; ++i)
            #pragma unroll
            for (int j = 0; j < 4; ++j) {
                acc[i][j] = __builtin_amdgcn_mfma_f32_16x16x32_bf16(ah[i], bh[j],  acc[i][j], 0, 0, 0);
                acc[i][j] = __builtin_amdgcn_mfma_f32_16x16x32_bf16(ah[i], blv[j], acc[i][j], 0, 0, 0);
                acc[i][j] = __builtin_amdgcn_mfma_f32_16x16x32_bf16(al[i], bh[j],  acc[i][j], 0, 0, 0);
            }
    }

    #pragma unroll
    for (int i = 0; i < 4; ++i)
        #pragma unroll
        for (int r = 0; r < 4; ++r) {
            int lr = wr * 64 + i * 16 + lg * 4 + r;
            #pragma unroll
            for (int j = 0; j < 4; ++j) {
                float v = acc[i][j][r] + bj[j];
                v = v > 0.0f ? v : expm1f(v);   // ELU
                cst[lr][n0 + j * 16 + l15] = v;
            }
        }
    __syncthreads();

    // per-graph segment reduce within block, few atomics to pooled
    const int col  = t & 127;
    const int half = t >> 7;          // rows [half*64, half*64+64)
    float run = 0.0f;
    int cur_g = -2;
    #pragma unroll 4
    for (int r = 0; r < 64; ++r) {
        int lr = half * 64 + r;
        int g = batch_s[lr];
        if (g != cur_g) {
            if (cur_g >= 0) atomicAdd(&pooled[cur_g * CPH + col], run);
            run = 0.0f; cur_g = g;
        }
        if (g >= 0) run += cst[lr][col];
    }
    if (cur_g >= 0) atomicAdd(&pooled[cur_g * CPH + col], run);
}

// ---- CSR build: single-block scan, 4 elems/thread ----
__global__ __launch_bounds__(256) void scan_kernel(
    const int* __restrict__ deg, int* __restrict__ rowptr, int* __restrict__ wof)
{
    __shared__ int wsum[4];
    __shared__ int carry_s;
    const int t = threadIdx.x, wave = t >> 6, lane = t & 63;
    if (t == 0) { carry_s = 0; rowptr[0] = 0; }
    __syncthreads();
    for (int base = 0; base < N_NODES; base += 1024) {
        int idx = base + t * 4;
        int d[4], p[4];
        #pragma unroll
        for (int k = 0; k < 4; ++k)
            d[k] = (idx + k < N_NODES) ? deg[idx + k] : 0;
        p[0] = d[0]; p[1] = p[0] + d[1]; p[2] = p[1] + d[2]; p[3] = p[2] + d[3];
        int v = p[3];
        #pragma unroll
        for (int off = 1; off < 64; off <<= 1) {
            int u = __shfl_up(v, off, 64);
            if (lane >= off) v += u;
        }
        if (lane == 63) wsum[wave] = v;
        __syncthreads();
        int woff = carry_s;
        #pragma unroll
        for (int w = 0; w < 4; ++w) if (w < wave) woff += wsum[w];
        int tbase = woff + v - p[3];
        #pragma unroll
        for (int k = 0; k < 4; ++k) {
            if (idx + k < N_NODES) {
                rowptr[idx + k + 1] = tbase + p[k];
                wof[idx + k] = tbase + p[k] - d[k];
            }
        }
        __syncthreads();
        if (t == 255) carry_s = woff + v;
        __syncthreads();
    }
}

// ---- CSR build: scatter edge src ids ----
__global__ void scatter_kernel(const int* __restrict__ ei, int* __restrict__ wof,
                               int* __restrict__ csr_src)
{
    for (int e = blockIdx.x * blockDim.x + threadIdx.x; e < ETOT;
         e += gridDim.x * blockDim.x) {
        int src, dst;
        if (e < N_EDGES) { src = ei[e]; dst = ei[N_EDGES + e]; }
        else             { src = dst = e - N_EDGES; }
        int p = atomicAdd(&wof[dst], 1);
        csr_src[p] = src;
    }
}

// ---- fused logits + online softmax + aggregation (bf16, pipelined gather) ----
__global__ __launch_bounds__(256) void agg_fused(
    const unsigned short* __restrict__ xl_h, const unsigned short* __restrict__ xr_h,
    const float* __restrict__ att,
    const int* __restrict__ rowptr, const int* __restrict__ csr_src,
    unsigned short* __restrict__ agg_h)
{
    const int dst = blockIdx.x;
    const int t = threadIdx.x;
    const int beg = rowptr[dst], end = rowptr[dst + 1];

    const u16x4 bh4 = *(const u16x4*)&xr_h[(size_t)dst * HCH + t * 4];
    f4v b;
    #pragma unroll
    for (int e = 0; e < 4; ++e) b[e] = bf16_to_f(bh4[e]);
    const f4v w = *(const f4v*)&att[t * 4];

    float m = -__builtin_inff(), s = 0.0f;
    f4v acc = {0.f, 0.f, 0.f, 0.f};

    u16x4 vh_nx = {0, 0, 0, 0};
    if (beg < end)
        vh_nx = *(const u16x4*)&xl_h[(size_t)csr_src[beg] * HCH + t * 4];

    for (int j = beg; j < end; ++j) {
        const u16x4 vh = vh_nx;
        if (j + 1 < end)    // prefetch next edge's row while computing this one
            vh_nx = *(const u16x4*)&xl_h[(size_t)csr_src[j + 1] * HCH + t * 4];

        f4v v;
        #pragma unroll
        for (int e = 0; e < 4; ++e) v[e] = bf16_to_f(vh[e]);
        float e0 = v[0] + b[0]; e0 = e0 > 0.f ? e0 : 0.2f * e0;
        float e1 = v[1] + b[1]; e1 = e1 > 0.f ? e1 : 0.2f * e1;
        float e2 = v[2] + b[2]; e2 = e2 > 0.f ? e2 : 0.2f * e2;
        float e3 = v[3] + b[3]; e3 = e3 > 0.f ? e3 : 0.2f * e3;
        float p = e0 * w[0] + e1 * w[1] + e2 * w[2] + e3 * w[3];
        #pragma unroll
        for (int off = 16; off; off >>= 1) p += __shfl_xor(p, off, 32);

        if (p > m) {
            float scale = __expf(m - p);   // first iter: exp(-inf)=0
            s = s * scale + 1.0f;
            acc = acc * scale + v;
            m = p;
        } else {
            float pw = __expf(p - m);
            s += pw;
            acc += v * pw;
        }
    }

    const float inv = 1.0f / (s + 1e-16f);
    f4v r = acc * inv;
    u16x4 hv;
    #pragma unroll
    for (int e = 0; e < 4; ++e) hv[e] = bf16_rne(r[e]);
    *(u16x4*)&agg_h[(size_t)dst * HCH + t * 4] = hv;
}

// ---- MLP head: one thread per graph (counts via binary search on batch) ----
__global__ __launch_bounds__(64) void head_kernel(
    const float* __restrict__ pooled, const int* __restrict__ batch,
    const float* __restrict__ W1, const float* __restrict__ b1,
    const float* __restrict__ W2, const float* __restrict__ b2,
    const float* __restrict__ W3, const float* __restrict__ b3,
    float* __restrict__ out)
{
    const int g = threadIdx.x;
    int lo = 0, hi = N_NODES;
    while (lo < hi) { int mid = (lo + hi) >> 1; if (batch[mid] <  g) lo = mid + 1; else hi = mid; }
    const int s0 = lo;
    hi = N_NODES;
    while (lo < hi) { int mid = (lo + hi) >> 1; if (batch[mid] <= g) lo = mid + 1; else hi = mid; }
    const float inv = 1.0f / fmaxf((float)(lo - s0), 1.0f);

    float y1[16];
    for (int j = 0; j < 16; ++j) {
        float s = b1[j];
        for (int k = 0; k < CPH; ++k) s += W1[j * CPH + k] * (pooled[g * CPH + k] * inv);
        y1[j] = fmaxf(s, 0.0f);
    }
    float y2[32];
    for (int j = 0; j < 32; ++j) {
        float s = b2[j];
        for (int k = 0; k < 16; ++k) s += W2[j * 16 + k] * y1[k];
        y2[j] = fmaxf(s, 0.0f);
    }
    for (int u = 0; u < 5; ++u) {
        float s = b3[u];
        for (int k = 0; k < 32; ++k) s += W3[u * 32 + k] * y2[k];
        out[g * 5 + u] = s;
    }
}

extern "C" void kernel_launch(void* const* d_in, const int* in_sizes, int n_in,
                              void* d_out, int out_size, void* d_ws, size_t ws_size,
                              hipStream_t stream)
{
    const float* x         = (const float*)d_in[0];
    const int*   ei        = (const int*)  d_in[1];
    const int*   batch     = (const int*)  d_in[2];
    const float* Wl        = (const float*)d_in[3];
    const float* bl        = (const float*)d_in[4];
    const float* Wr        = (const float*)d_in[5];
    const float* br        = (const float*)d_in[6];
    const float* att       = (const float*)d_in[7];
    const float* Wres      = (const float*)d_in[8];
    const float* bias_conv = (const float*)d_in[9];
    const float* Wlin      = (const float*)d_in[10];
    const float* blin      = (const float*)d_in[11];
    const float* W1        = (const float*)d_in[12];
    const float* b1        = (const float*)d_in[13];
    const float* W2        = (const float*)d_in[14];
    const float* b2        = (const float*)d_in[15];
    const float* W3        = (const float*)d_in[16];
    const float* b3        = (const float*)d_in[17];
    float* out = (float*)d_out;

    // ---- workspace layout (~137 MB) ----
    unsigned short* xl_h  = (unsigned short*)d_ws;              // N*HCH u16 41 MB
    unsigned short* xr_h  = xl_h + (size_t)N_NODES * HCH;       // N*HCH u16 41 MB
    unsigned short* agg_h = xr_h + (size_t)N_NODES * HCH;       // N*HCH u16 41 MB
    float* pooled = (float*)(agg_h + (size_t)N_NODES * HCH);    // NG*CPH f
    float* bcomb  = pooled + NG * CPH;                          // 128 f
    unsigned short* x_hi  = (unsigned short*)(bcomb + 128);     // N*IN u16
    unsigned short* x_lo  = x_hi  + (size_t)N_NODES * IN_CH;
    unsigned short* wl_hi = x_lo  + (size_t)N_NODES * IN_CH;
    unsigned short* wl_lo = wl_hi + HCH * IN_CH;
    unsigned short* wr_hi = wl_lo + HCH * IN_CH;
    unsigned short* wr_lo = wr_hi + HCH * IN_CH;
    unsigned short* wn_hi = wr_lo + HCH * IN_CH;
    unsigned short* wn_lo = wn_hi + CPH * HCH;
    unsigned short* wc_hi = wn_lo + CPH * HCH;
    unsigned short* wc_lo = wc_hi + CPH * IN_CH;
    int* deg     = (int*)(wc_lo + CPH * IN_CH);                 // N
    int* rowptr  = deg + N_NODES;                               // N+1
    int* wof     = rowptr + N_NODES + 1;                        // N
    int* csr_src = wof + N_NODES;                               // ETOT

    init_kernel<<<(N_NODES + 255) / 256, 256, 0, stream>>>(deg, pooled);

    cvt_all<<<NCVT + 128, 256, 0, stream>>>(x, Wl, Wr, Wlin,
                                            x_hi, x_lo, wl_hi, wl_lo,
                                            wr_hi, wr_lo, wn_hi, wn_lo,
                                            ei, deg,
                                            Wres, bias_conv, blin,
                                            wc_hi, wc_lo, bcomb);

    dim3 gp((N_NODES + 127) / 128, 16);
    proj_gemm<<<gp, 256, 0, stream>>>(x_hi, x_lo, wl_hi, wl_lo, wr_hi, wr_lo,
                                      bl, br, xl_h, xr_h, N_NODES);

    scan_kernel<<<1, 256, 0, stream>>>(deg, rowptr, wof);
    scatter_kernel<<<1024, 256, 0, stream>>>(ei, wof, csr_src);

    agg_fused<<<N_NODES, 256, 0, stream>>>(xl_h, xr_h, att, rowptr, csr_src, agg_h);

    dim3 g2((N_NODES + 127) / 128, 1);
    mfma_gemm2<<<g2, 256, 0, stream>>>(agg_h, wn_hi, wn_lo, HCH,
                                       x_hi, x_lo, wc_hi, wc_lo, IN_CH,
                                       bcomb, batch, pooled, N_NODES);

    head_kernel<<<1, 64, 0, stream>>>(pooled, batch, W1, b1, W2, b2, W3, b3, out);
}

// Round 9
// 432.829 us; speedup vs baseline: 13.1410x; 1.0523x over previous
//
#include <hip/hip_runtime.h>
#include <hip/hip_bf16.h>
#include <math.h>

#define N_NODES 20000
#define N_EDGES 320000
#define IN_CH   128
#define HEADS   8
#define CPH     128
#define HCH     1024
#define NG      64
#define ETOT    (N_EDGES + N_NODES)
#define NCVT    768

typedef __attribute__((ext_vector_type(8))) short s8v;
typedef __attribute__((ext_vector_type(4))) float f4v;
typedef __attribute__((ext_vector_type(4))) unsigned short u16x4;

// ---- fp32 -> bf16 split helpers (RNE) ----
__device__ __forceinline__ unsigned short bf16_rne(float f) {
    unsigned u = __float_as_uint(f);
    unsigned r = u + 0x7fffu + ((u >> 16) & 1u);
    return (unsigned short)(r >> 16);
}
__device__ __forceinline__ float bf16_to_f(unsigned short h) {
    return __uint_as_float((unsigned)h << 16);
}

// ---- zero deg + pooled ----
__global__ void init_kernel(int* __restrict__ deg, float* __restrict__ pooled) {
    int i = blockIdx.x * blockDim.x + threadIdx.x;
    if (i < N_NODES) deg[i] = 0;
    if (i < NG * CPH) pooled[i] = 0.0f;
}

// ---- fp32 -> (hi,lo) bf16 planes + edge histogram + wcomb (merged) ----
__global__ void cvt_all(const float* __restrict__ x,  const float* __restrict__ Wl,
                        const float* __restrict__ Wr, const float* __restrict__ Wlin,
                        unsigned short* __restrict__ xhi,  unsigned short* __restrict__ xlo,
                        unsigned short* __restrict__ wlhi, unsigned short* __restrict__ wllo,
                        unsigned short* __restrict__ wrhi, unsigned short* __restrict__ wrlo,
                        unsigned short* __restrict__ wnhi, unsigned short* __restrict__ wnlo,
                        const int* __restrict__ ei, int* __restrict__ deg,
                        const float* __restrict__ Wres, const float* __restrict__ bias_conv,
                        const float* __restrict__ blin,
                        unsigned short* __restrict__ wchi, unsigned short* __restrict__ wclo,
                        float* __restrict__ bcomb)
{
    const int t = threadIdx.x;
    if (blockIdx.x < NCVT) {
        const int NX = N_NODES * IN_CH, NW = HCH * IN_CH;
        const int TOT4 = (NX + 3 * NW) >> 2;
        const int stride = NCVT * 256;
        for (int q = blockIdx.x * 256 + t; q < TOT4; q += stride) {
            int i = q << 2;
            const float* s; unsigned short *hi, *lo; int k;
            if (i < NX)               { s = x;    hi = xhi;  lo = xlo;  k = i; }
            else if (i < NX + NW)     { s = Wl;   hi = wlhi; lo = wllo; k = i - NX; }
            else if (i < NX + 2 * NW) { s = Wr;   hi = wrhi; lo = wrlo; k = i - NX - NW; }
            else                      { s = Wlin; hi = wnhi; lo = wnlo; k = i - NX - 2 * NW; }
            f4v f = *(const f4v*)&s[k];
            u16x4 h, l;
            #pragma unroll
            for (int e = 0; e < 4; ++e) {
                unsigned short hh = bf16_rne(f[e]);
                h[e] = hh;
                l[e] = bf16_rne(f[e] - bf16_to_f(hh));
            }
            *(u16x4*)&hi[k] = h;
            *(u16x4*)&lo[k] = l;
        }
        for (int e = blockIdx.x * 256 + t; e < ETOT; e += stride) {
            int dst = (e < N_EDGES) ? ei[N_EDGES + e] : (e - N_EDGES);
            atomicAdd(&deg[dst], 1);
        }
    } else if (t < 128) {
        // Wcomb = Wlin @ Wres, bcomb = blin + Wlin @ bias_conv
        const int j = blockIdx.x - NCVT;    // 0..127
        float s = 0.0f, pb = 0.0f;
        for (int m = 0; m < HCH; ++m) {
            float wl = Wlin[j * HCH + m];
            s  += wl * Wres[m * IN_CH + t];
            pb += wl * bias_conv[m];
        }
        unsigned short h = bf16_rne(s);
        wchi[j * IN_CH + t] = h;
        wclo[j * IN_CH + t] = bf16_rne(s - bf16_to_f(h));
        if (t == 0) bcomb[j] = blin[j] + pb;
    }
}

// ---- merged projection GEMM: xl/xr(bf16) = x@W.T+b, plus dl/dr = att-dot ----
__global__ __launch_bounds__(256) void proj_gemm(
    const unsigned short* __restrict__ Ahi, const unsigned short* __restrict__ Alo,
    const unsigned short* __restrict__ WLhi, const unsigned short* __restrict__ WLlo,
    const unsigned short* __restrict__ WRhi, const unsigned short* __restrict__ WRlo,
    const float* __restrict__ bl, const float* __restrict__ br,
    const float* __restrict__ att,
    unsigned short* __restrict__ xl_h, unsigned short* __restrict__ xr_h,
    float* __restrict__ dl, float* __restrict__ dr, int M)
{
    __shared__ float cst[128][130];
    const int t    = threadIdx.x;
    const int wave = t >> 6, lane = t & 63;
    const int wr = wave >> 1, wc = wave & 1;
    const int l15 = lane & 15, lg = lane >> 4;
    const int m0 = blockIdx.x * 128 + wr * 64;
    const int by = blockIdx.y;
    const int sel = by >> 3;
    const int hh  = by & 7;
    const int col0 = hh * 128;
    const unsigned short* Whi = sel ? WRhi : WLhi;
    const unsigned short* Wlo = sel ? WRlo : WLlo;
    const float* bias = sel ? br : bl;
    unsigned short* C = sel ? xr_h : xl_h;
    float* D = sel ? dr : dl;
    const int koff = lg * 8;
    const int K = IN_CH;

    int rowA[4], colB[4];
    #pragma unroll
    for (int i = 0; i < 4; ++i) { int r = m0 + i * 16 + l15; rowA[i] = r < M ? r : M - 1; }
    #pragma unroll
    for (int j = 0; j < 4; ++j) colB[j] = col0 + wc * 64 + j * 16 + l15;

    float bj[4];
    #pragma unroll
    for (int j = 0; j < 4; ++j) bj[j] = bias[colB[j]];

    f4v acc[4][4];
    #pragma unroll
    for (int i = 0; i < 4; ++i)
        #pragma unroll
        for (int j = 0; j < 4; ++j) acc[i][j] = (f4v){0.f, 0.f, 0.f, 0.f};

    for (int k0 = 0; k0 < K; k0 += 32) {
        s8v ah[4], al[4], bh[4], blv[4];
        #pragma unroll
        for (int i = 0; i < 4; ++i) {
            size_t off = (size_t)rowA[i] * K + k0 + koff;
            ah[i] = *(const s8v*)&Ahi[off];
            al[i] = *(const s8v*)&Alo[off];
        }
        #pragma unroll
        for (int j = 0; j < 4; ++j) {
            size_t off = (size_t)colB[j] * K + k0 + koff;
            bh[j]  = *(const s8v*)&Whi[off];
            blv[j] = *(const s8v*)&Wlo[off];
        }
        #pragma unroll
        for (int i = 0; i < 4; ++i)
            #pragma unroll
            for (int j = 0; j < 4; ++j) {
                acc[i][j] = __builtin_amdgcn_mfma_f32_16x16x32_bf16(ah[i], bh[j],  acc[i][j], 0, 0, 0);
                acc[i][j] = __builtin_amdgcn_mfma_f32_16x16x32_bf16(ah[i], blv[j], acc[i][j], 0, 0, 0);
                acc[i][j] = __builtin_amdgcn_mfma_f32_16x16x32_bf16(al[i], bh[j],  acc[i][j], 0, 0, 0);
            }
    }

    #pragma unroll
    for (int i = 0; i < 4; ++i)
        #pragma unroll
        for (int r = 0; r < 4; ++r) {
            int lr = wr * 64 + i * 16 + lg * 4 + r;
            #pragma unroll
            for (int j = 0; j < 4; ++j)
                cst[lr][wc * 64 + j * 16 + l15] = acc[i][j][r] + bj[j];
        }
    __syncthreads();

    // coalesced bf16 store
    {
        const int c4 = t & 31;
        const int r8 = t >> 5;
        #pragma unroll
        for (int it = 0; it < 16; ++it) {
            int lr = it * 8 + r8;
            int row = blockIdx.x * 128 + lr;
            if (row >= M) continue;
            f4v v = *(const f4v*)&cst[lr][c4 * 4];
            u16x4 hv;
            #pragma unroll
            for (int e = 0; e < 4; ++e) hv[e] = bf16_rne(v[e]);
            *(u16x4*)&C[(size_t)row * HCH + col0 + c4 * 4] = hv;
        }
    }

    // att-dot per row for this head: D[row*8+hh] = sum_c att[hh*128+c] * cst[row][c]
    {
        const int r2  = t >> 1;            // row 0..127
        const int ch0 = (t & 1) * 64;      // half of the 128 channels
        float q = 0.0f;
        #pragma unroll 8
        for (int c = 0; c < 64; c += 4) {
            f4v av = *(const f4v*)&att[hh * 128 + ch0 + c];
            f4v cv = *(const f4v*)&cst[r2][ch0 + c];
            q = fmaf(av[0], cv[0], q); q = fmaf(av[1], cv[1], q);
            q = fmaf(av[2], cv[2], q); q = fmaf(av[3], cv[3], q);
        }
        q += __shfl_xor(q, 1, 64);         // pair (2r,2r+1) within same wave
        int row = blockIdx.x * 128 + r2;
        if ((t & 1) == 0 && row < M) D[row * 8 + hh] = q;
    }
}

// ---- final GEMM + ELU + fused pooling: 64-row tile, 2 waves, 313 blocks ----
__global__ __launch_bounds__(128) void mfma_gemm2(
    const unsigned short* __restrict__ A1h,
    const unsigned short* __restrict__ B1hi, const unsigned short* __restrict__ B1lo, int K1,
    const unsigned short* __restrict__ A2hi, const unsigned short* __restrict__ A2lo,
    const unsigned short* __restrict__ B2hi, const unsigned short* __restrict__ B2lo, int K2,
    const float* __restrict__ bias, const int* __restrict__ batch,
    float* __restrict__ pooled, int M)
{
    __shared__ float cst[64][130];
    __shared__ int batch_s[64];
    const int t    = threadIdx.x;
    const int wc   = t >> 6, lane = t & 63;
    const int l15 = lane & 15, lg = lane >> 4;
    const int m0 = blockIdx.x * 64;
    const int n0 = wc * 64;
    const int koff = lg * 8;

    if (t < 64) {
        int row = m0 + t;
        batch_s[t] = (row < M) ? batch[row] : -1;
    }

    int rowA[4], colB[4];
    #pragma unroll
    for (int i = 0; i < 4; ++i) { int r = m0 + i * 16 + l15; rowA[i] = r < M ? r : M - 1; }
    #pragma unroll
    for (int j = 0; j < 4; ++j) colB[j] = n0 + j * 16 + l15;

    float bj[4];
    #pragma unroll
    for (int j = 0; j < 4; ++j) bj[j] = bias[colB[j]];

    f4v acc[4][4];
    #pragma unroll
    for (int i = 0; i < 4; ++i)
        #pragma unroll
        for (int j = 0; j < 4; ++j) acc[i][j] = (f4v){0.f, 0.f, 0.f, 0.f};

    for (int k0 = 0; k0 < K1; k0 += 32) {
        s8v ah[4], bh[4], blv[4];
        #pragma unroll
        for (int i = 0; i < 4; ++i)
            ah[i] = *(const s8v*)&A1h[(size_t)rowA[i] * K1 + k0 + koff];
        #pragma unroll
        for (int j = 0; j < 4; ++j) {
            size_t off = (size_t)colB[j] * K1 + k0 + koff;
            bh[j]  = *(const s8v*)&B1hi[off];
            blv[j] = *(const s8v*)&B1lo[off];
        }
        #pragma unroll
        for (int i = 0; i < 4; ++i)
            #pragma unroll
            for (int j = 0; j < 4; ++j) {
                acc[i][j] = __builtin_amdgcn_mfma_f32_16x16x32_bf16(ah[i], bh[j],  acc[i][j], 0, 0, 0);
                acc[i][j] = __builtin_amdgcn_mfma_f32_16x16x32_bf16(ah[i], blv[j], acc[i][j], 0, 0, 0);
            }
    }
    for (int k0 = 0; k0 < K2; k0 += 32) {
        s8v ah[4], al[4], bh[4], blv[4];
        #pragma unroll
        for (int i = 0; i < 4; ++i) {
            size_t off = (size_t)rowA[i] * K2 + k0 + koff;
            ah[i] = *(const s8v*)&A2hi[off];
            al[i] = *(const s8v*)&A2lo[off];
        }
        #pragma unroll
        for (int j = 0; j < 4; ++j) {
            size_t off = (size_t)colB[j] * K2 + k0 + koff;
            bh[j]  = *(const s8v*)&B2hi[off];
            blv[j] = *(const s8v*)&B2lo[off];
        }
        #pragma unroll
        for (int i = 0; i < 4; ++i)
            #pragma unroll
            for (int j = 0; j < 4; ++j) {
                acc[i][j] = __builtin_amdgcn_mfma_f32_16x16x32_bf16(ah[i], bh[j],  acc[i][j], 0, 0, 0);
                acc[i][j] = __builtin_amdgcn_mfma_f32_16x16x32_bf16(ah[i], blv[j], acc[i][j], 0, 0, 0);
                acc[i][j] = __builtin_amdgcn_mfma_f32_16x16x32_bf16(al[i], bh[j],  acc[i][j], 0, 0, 0);
            }
    }

    #pragma unroll
    for (int i = 0; i < 4; ++i)
        #pragma unroll
        for (int r = 0; r < 4; ++r) {
            int lr = i * 16 + lg * 4 + r;
            #pragma unroll
            for (int j = 0; j < 4; ++j) {
                float v = acc[i][j][r] + bj[j];
                v = v > 0.0f ? v : expm1f(v);   // ELU
                cst[lr][n0 + j * 16 + l15] = v;
            }
        }
    __syncthreads();

    // per-graph segment reduce: thread t owns column t over 64 rows
    const int col = t;
    float run = 0.0f;
    int cur_g = -2;
    #pragma unroll 4
    for (int r = 0; r < 64; ++r) {
        int g = batch_s[r];
        if (g != cur_g) {
            if (cur_g >= 0) atomicAdd(&pooled[cur_g * CPH + col], run);
            run = 0.0f; cur_g = g;
        }
        if (g >= 0) run += cst[r][col];
    }
    if (cur_g >= 0) atomicAdd(&pooled[cur_g * CPH + col], run);
}

// ---- CSR build: single-block scan, 4 elems/thread ----
__global__ __launch_bounds__(256) void scan_kernel(
    const int* __restrict__ deg, int* __restrict__ rowptr, int* __restrict__ wof)
{
    __shared__ int wsum[4];
    __shared__ int carry_s;
    const int t = threadIdx.x, wave = t >> 6, lane = t & 63;
    if (t == 0) { carry_s = 0; rowptr[0] = 0; }
    __syncthreads();
    for (int base = 0; base < N_NODES; base += 1024) {
        int idx = base + t * 4;
        int d[4], p[4];
        #pragma unroll
        for (int k = 0; k < 4; ++k)
            d[k] = (idx + k < N_NODES) ? deg[idx + k] : 0;
        p[0] = d[0]; p[1] = p[0] + d[1]; p[2] = p[1] + d[2]; p[3] = p[2] + d[3];
        int v = p[3];
        #pragma unroll
        for (int off = 1; off < 64; off <<= 1) {
            int u = __shfl_up(v, off, 64);
            if (lane >= off) v += u;
        }
        if (lane == 63) wsum[wave] = v;
        __syncthreads();
        int woff = carry_s;
        #pragma unroll
        for (int w = 0; w < 4; ++w) if (w < wave) woff += wsum[w];
        int tbase = woff + v - p[3];
        #pragma unroll
        for (int k = 0; k < 4; ++k) {
            if (idx + k < N_NODES) {
                rowptr[idx + k + 1] = tbase + p[k];
                wof[idx + k] = tbase + p[k] - d[k];
            }
        }
        __syncthreads();
        if (t == 255) carry_s = woff + v;
        __syncthreads();
    }
}

// ---- CSR build: scatter edge src ids ----
__global__ void scatter_kernel(const int* __restrict__ ei, int* __restrict__ wof,
                               int* __restrict__ csr_src)
{
    for (int e = blockIdx.x * blockDim.x + threadIdx.x; e < ETOT;
         e += gridDim.x * blockDim.x) {
        int src, dst;
        if (e < N_EDGES) { src = ei[e]; dst = ei[N_EDGES + e]; }
        else             { src = dst = e - N_EDGES; }
        int p = atomicAdd(&wof[dst], 1);
        csr_src[p] = src;
    }
}

// ---- fused logits + online softmax + aggregation ----
// leaky(y) = 0.6y + 0.4|y|  =>  logit = 0.6(dl[src]+dr[dst]) + sum(0.4*att*|y|)
__global__ __launch_bounds__(256) void agg_fused(
    const unsigned short* __restrict__ xl_h, const unsigned short* __restrict__ xr_h,
    const float* __restrict__ att,
    const float* __restrict__ dl, const float* __restrict__ dr,
    const int* __restrict__ rowptr, const int* __restrict__ csr_src,
    unsigned short* __restrict__ agg_h)
{
    const int dst = blockIdx.x;
    const int t = threadIdx.x;
    const int h = t >> 5;
    const int beg = rowptr[dst], end = rowptr[dst + 1];

    const u16x4 bh4 = *(const u16x4*)&xr_h[(size_t)dst * HCH + t * 4];
    f4v b;
    #pragma unroll
    for (int e = 0; e < 4; ++e) b[e] = bf16_to_f(bh4[e]);
    f4v w04 = 0.4f * (*(const f4v*)&att[t * 4]);
    const float pb = 0.6f * dr[dst * 8 + h];

    float m = -__builtin_inff(), s = 0.0f;
    f4v acc = {0.f, 0.f, 0.f, 0.f};

    int j = beg;
    for (; j + 1 < end; j += 2) {
        const int s0 = csr_src[j], s1 = csr_src[j + 1];
        const u16x4 vh0 = *(const u16x4*)&xl_h[(size_t)s0 * HCH + t * 4];
        const u16x4 vh1 = *(const u16x4*)&xl_h[(size_t)s1 * HCH + t * 4];
        const float d0 = dl[s0 * 8 + h], d1 = dl[s1 * 8 + h];
        f4v v0, v1;
        #pragma unroll
        for (int e = 0; e < 4; ++e) { v0[e] = bf16_to_f(vh0[e]); v1[e] = bf16_to_f(vh1[e]); }

        float q0 = w04[0] * __builtin_fabsf(v0[0] + b[0]);
        float q1 = w04[0] * __builtin_fabsf(v1[0] + b[0]);
        #pragma unroll
        for (int e = 1; e < 4; ++e) {
            q0 = fmaf(w04[e], __builtin_fabsf(v0[e] + b[e]), q0);
            q1 = fmaf(w04[e], __builtin_fabsf(v1[e] + b[e]), q1);
        }
        #pragma unroll
        for (int off = 16; off; off >>= 1) {
            q0 += __shfl_xor(q0, off, 32);
            q1 += __shfl_xor(q1, off, 32);
        }
        const float p0 = fmaf(0.6f, d0, q0) + pb;
        const float p1 = fmaf(0.6f, d1, q1) + pb;

        const float mx = fmaxf(p0, p1);
        if (mx > m) {
            float scale = __expf(m - mx);   // first pair: exp(-inf)=0
            float e0 = __expf(p0 - mx), e1 = __expf(p1 - mx);
            s = s * scale + e0 + e1;
            acc = acc * scale + v0 * e0 + v1 * e1;
            m = mx;
        } else {
            float e0 = __expf(p0 - m), e1 = __expf(p1 - m);
            s += e0 + e1;
            acc += v0 * e0 + v1 * e1;
        }
    }
    if (j < end) {   // tail edge
        const int s0 = csr_src[j];
        const u16x4 vh0 = *(const u16x4*)&xl_h[(size_t)s0 * HCH + t * 4];
        const float d0 = dl[s0 * 8 + h];
        f4v v0;
        #pragma unroll
        for (int e = 0; e < 4; ++e) v0[e] = bf16_to_f(vh0[e]);
        float q0 = w04[0] * __builtin_fabsf(v0[0] + b[0]);
        #pragma unroll
        for (int e = 1; e < 4; ++e)
            q0 = fmaf(w04[e], __builtin_fabsf(v0[e] + b[e]), q0);
        #pragma unroll
        for (int off = 16; off; off >>= 1) q0 += __shfl_xor(q0, off, 32);
        const float p0 = fmaf(0.6f, d0, q0) + pb;
        if (p0 > m) {
            float scale = __expf(m - p0);
            s = s * scale + 1.0f;
            acc = acc * scale + v0;
            m = p0;
        } else {
            float e0 = __expf(p0 - m);
            s += e0;
            acc += v0 * e0;
        }
    }

    const float inv = 1.0f / (s + 1e-16f);
    f4v r = acc * inv;
    u16x4 hv;
    #pragma unroll
    for (int e = 0; e < 4; ++e) hv[e] = bf16_rne(r[e]);
    *(u16x4*)&agg_h[(size_t)dst * HCH + t * 4] = hv;
}

// ---- MLP head: one thread per graph (counts via binary search on batch) ----
__global__ __launch_bounds__(64) void head_kernel(
    const float* __restrict__ pooled, const int* __restrict__ batch,
    const float* __restrict__ W1, const float* __restrict__ b1,
    const float* __restrict__ W2, const float* __restrict__ b2,
    const float* __restrict__ W3, const float* __restrict__ b3,
    float* __restrict__ out)
{
    const int g = threadIdx.x;
    int lo = 0, hi = N_NODES;
    while (lo < hi) { int mid = (lo + hi) >> 1; if (batch[mid] <  g) lo = mid + 1; else hi = mid; }
    const int s0 = lo;
    hi = N_NODES;
    while (lo < hi) { int mid = (lo + hi) >> 1; if (batch[mid] <= g) lo = mid + 1; else hi = mid; }
    const float inv = 1.0f / fmaxf((float)(lo - s0), 1.0f);

    float y1[16];
    for (int j = 0; j < 16; ++j) {
        float s = b1[j];
        for (int k = 0; k < CPH; ++k) s += W1[j * CPH + k] * (pooled[g * CPH + k] * inv);
        y1[j] = fmaxf(s, 0.0f);
    }
    float y2[32];
    for (int j = 0; j < 32; ++j) {
        float s = b2[j];
        for (int k = 0; k < 16; ++k) s += W2[j * 16 + k] * y1[k];
        y2[j] = fmaxf(s, 0.0f);
    }
    for (int u = 0; u < 5; ++u) {
        float s = b3[u];
        for (int k = 0; k < 32; ++k) s += W3[u * 32 + k] * y2[k];
        out[g * 5 + u] = s;
    }
}

extern "C" void kernel_launch(void* const* d_in, const int* in_sizes, int n_in,
                              void* d_out, int out_size, void* d_ws, size_t ws_size,
                              hipStream_t stream)
{
    const float* x         = (const float*)d_in[0];
    const int*   ei        = (const int*)  d_in[1];
    const int*   batch     = (const int*)  d_in[2];
    const float* Wl        = (const float*)d_in[3];
    const float* bl        = (const float*)d_in[4];
    const float* Wr        = (const float*)d_in[5];
    const float* br        = (const float*)d_in[6];
    const float* att       = (const float*)d_in[7];
    const float* Wres      = (const float*)d_in[8];
    const float* bias_conv = (const float*)d_in[9];
    const float* Wlin      = (const float*)d_in[10];
    const float* blin      = (const float*)d_in[11];
    const float* W1        = (const float*)d_in[12];
    const float* b1        = (const float*)d_in[13];
    const float* W2        = (const float*)d_in[14];
    const float* b2        = (const float*)d_in[15];
    const float* W3        = (const float*)d_in[16];
    const float* b3        = (const float*)d_in[17];
    float* out = (float*)d_out;

    // ---- workspace layout (~139 MB) ----
    unsigned short* xl_h  = (unsigned short*)d_ws;              // N*HCH u16 41 MB
    unsigned short* xr_h  = xl_h + (size_t)N_NODES * HCH;       // N*HCH u16 41 MB
    unsigned short* agg_h = xr_h + (size_t)N_NODES * HCH;       // N*HCH u16 41 MB
    float* pooled = (float*)(agg_h + (size_t)N_NODES * HCH);    // NG*CPH f
    float* bcomb  = pooled + NG * CPH;                          // 128 f
    float* dl     = bcomb + 128;                                // N*8 f
    float* dr     = dl + (size_t)N_NODES * 8;                   // N*8 f
    unsigned short* x_hi  = (unsigned short*)(dr + (size_t)N_NODES * 8);
    unsigned short* x_lo  = x_hi  + (size_t)N_NODES * IN_CH;
    unsigned short* wl_hi = x_lo  + (size_t)N_NODES * IN_CH;
    unsigned short* wl_lo = wl_hi + HCH * IN_CH;
    unsigned short* wr_hi = wl_lo + HCH * IN_CH;
    unsigned short* wr_lo = wr_hi + HCH * IN_CH;
    unsigned short* wn_hi = wr_lo + HCH * IN_CH;
    unsigned short* wn_lo = wn_hi + CPH * HCH;
    unsigned short* wc_hi = wn_lo + CPH * HCH;
    unsigned short* wc_lo = wc_hi + CPH * IN_CH;
    int* deg     = (int*)(wc_lo + CPH * IN_CH);                 // N
    int* rowptr  = deg + N_NODES;                               // N+1
    int* wof     = rowptr + N_NODES + 1;                        // N
    int* csr_src = wof + N_NODES;                               // ETOT

    init_kernel<<<(N_NODES + 255) / 256, 256, 0, stream>>>(deg, pooled);

    cvt_all<<<NCVT + 128, 256, 0, stream>>>(x, Wl, Wr, Wlin,
                                            x_hi, x_lo, wl_hi, wl_lo,
                                            wr_hi, wr_lo, wn_hi, wn_lo,
                                            ei, deg,
                                            Wres, bias_conv, blin,
                                            wc_hi, wc_lo, bcomb);

    dim3 gp((N_NODES + 127) / 128, 16);
    proj_gemm<<<gp, 256, 0, stream>>>(x_hi, x_lo, wl_hi, wl_lo, wr_hi, wr_lo,
                                      bl, br, att, xl_h, xr_h, dl, dr, N_NODES);

    scan_kernel<<<1, 256, 0, stream>>>(deg, rowptr, wof);
    scatter_kernel<<<1024, 256, 0, stream>>>(ei, wof, csr_src);

    agg_fused<<<N_NODES, 256, 0, stream>>>(xl_h, xr_h, att, dl, dr,
                                           rowptr, csr_src, agg_h);

    dim3 g2((N_NODES + 63) / 64, 1);
    mfma_gemm2<<<g2, 128, 0, stream>>>(agg_h, wn_hi, wn_lo, HCH,
                                       x_hi, x_lo, wc_hi, wc_lo, IN_CH,
                                       bcomb, batch, pooled, N_NODES);

    head_kernel<<<1, 64, 0, stream>>>(pooled, batch, W1, b1, W2, b2, W3, b3, out);
}

// Round 10
// 426.711 us; speedup vs baseline: 13.3294x; 1.0143x over previous
//
#include <hip/hip_runtime.h>
#include <hip/hip_bf16.h>
#include <math.h>

#define N_NODES 20000
#define N_EDGES 320000
#define IN_CH   128
#define HEADS   8
#define CPH     128
#define HCH     1024
#define NG      64
#define ETOT    (N_EDGES + N_NODES)
#define NCVT    768

typedef __attribute__((ext_vector_type(8))) short s8v;
typedef __attribute__((ext_vector_type(4))) float f4v;
typedef __attribute__((ext_vector_type(8))) float f8v;
typedef __attribute__((ext_vector_type(4))) unsigned short u16x4;
typedef __attribute__((ext_vector_type(8))) unsigned short u16x8;

// ---- fp32 -> bf16 split helpers (RNE) ----
__device__ __forceinline__ unsigned short bf16_rne(float f) {
    unsigned u = __float_as_uint(f);
    unsigned r = u + 0x7fffu + ((u >> 16) & 1u);
    return (unsigned short)(r >> 16);
}
__device__ __forceinline__ float bf16_to_f(unsigned short h) {
    return __uint_as_float((unsigned)h << 16);
}

// ---- zero deg + pooled ----
__global__ void init_kernel(int* __restrict__ deg, float* __restrict__ pooled) {
    int i = blockIdx.x * blockDim.x + threadIdx.x;
    if (i < N_NODES) deg[i] = 0;
    if (i < NG * CPH) pooled[i] = 0.0f;
}

// ---- fp32 -> (hi,lo) bf16 planes + edge histogram + wcomb (merged) ----
__global__ void cvt_all(const float* __restrict__ x,  const float* __restrict__ Wl,
                        const float* __restrict__ Wr, const float* __restrict__ Wlin,
                        unsigned short* __restrict__ xhi,  unsigned short* __restrict__ xlo,
                        unsigned short* __restrict__ wlhi, unsigned short* __restrict__ wllo,
                        unsigned short* __restrict__ wrhi, unsigned short* __restrict__ wrlo,
                        unsigned short* __restrict__ wnhi, unsigned short* __restrict__ wnlo,
                        const int* __restrict__ ei, int* __restrict__ deg,
                        const float* __restrict__ Wres, const float* __restrict__ bias_conv,
                        const float* __restrict__ blin,
                        unsigned short* __restrict__ wchi, unsigned short* __restrict__ wclo,
                        float* __restrict__ bcomb)
{
    const int t = threadIdx.x;
    if (blockIdx.x < NCVT) {
        const int NX = N_NODES * IN_CH, NW = HCH * IN_CH;
        const int TOT4 = (NX + 3 * NW) >> 2;
        const int stride = NCVT * 256;
        for (int q = blockIdx.x * 256 + t; q < TOT4; q += stride) {
            int i = q << 2;
            const float* s; unsigned short *hi, *lo; int k;
            if (i < NX)               { s = x;    hi = xhi;  lo = xlo;  k = i; }
            else if (i < NX + NW)     { s = Wl;   hi = wlhi; lo = wllo; k = i - NX; }
            else if (i < NX + 2 * NW) { s = Wr;   hi = wrhi; lo = wrlo; k = i - NX - NW; }
            else                      { s = Wlin; hi = wnhi; lo = wnlo; k = i - NX - 2 * NW; }
            f4v f = *(const f4v*)&s[k];
            u16x4 h, l;
            #pragma unroll
            for (int e = 0; e < 4; ++e) {
                unsigned short hh = bf16_rne(f[e]);
                h[e] = hh;
                l[e] = bf16_rne(f[e] - bf16_to_f(hh));
            }
            *(u16x4*)&hi[k] = h;
            *(u16x4*)&lo[k] = l;
        }
        for (int e = blockIdx.x * 256 + t; e < ETOT; e += stride) {
            int dst = (e < N_EDGES) ? ei[N_EDGES + e] : (e - N_EDGES);
            atomicAdd(&deg[dst], 1);
        }
    } else if (t < 128) {
        // Wcomb = Wlin @ Wres, bcomb = blin + Wlin @ bias_conv
        const int j = blockIdx.x - NCVT;    // 0..127
        float s = 0.0f, pb = 0.0f;
        for (int m = 0; m < HCH; ++m) {
            float wl = Wlin[j * HCH + m];
            s  += wl * Wres[m * IN_CH + t];
            pb += wl * bias_conv[m];
        }
        unsigned short h = bf16_rne(s);
        wchi[j * IN_CH + t] = h;
        wclo[j * IN_CH + t] = bf16_rne(s - bf16_to_f(h));
        if (t == 0) bcomb[j] = blin[j] + pb;
    }
}

// ---- merged projection GEMM: xl/xr(bf16) = x@W.T+b, plus dl/dr att-dot ----
// bf16 LDS staging (33 KB -> higher occupancy); dl/dr computed from the
// bf16-rounded values so the leaky decomposition is exact.
__global__ __launch_bounds__(256) void proj_gemm(
    const unsigned short* __restrict__ Ahi, const unsigned short* __restrict__ Alo,
    const unsigned short* __restrict__ WLhi, const unsigned short* __restrict__ WLlo,
    const unsigned short* __restrict__ WRhi, const unsigned short* __restrict__ WRlo,
    const float* __restrict__ bl, const float* __restrict__ br,
    const float* __restrict__ att,
    unsigned short* __restrict__ xl_h, unsigned short* __restrict__ xr_h,
    float* __restrict__ dl, float* __restrict__ dr, int M)
{
    __shared__ unsigned short cst[128][136];
    const int t    = threadIdx.x;
    const int wave = t >> 6, lane = t & 63;
    const int wr = wave >> 1, wc = wave & 1;
    const int l15 = lane & 15, lg = lane >> 4;
    const int m0 = blockIdx.x * 128 + wr * 64;
    const int by = blockIdx.y;
    const int sel = by >> 3;
    const int hh  = by & 7;
    const int col0 = hh * 128;
    const unsigned short* Whi = sel ? WRhi : WLhi;
    const unsigned short* Wlo = sel ? WRlo : WLlo;
    const float* bias = sel ? br : bl;
    unsigned short* C = sel ? xr_h : xl_h;
    float* D = sel ? dr : dl;
    const int koff = lg * 8;
    const int K = IN_CH;

    int rowA[4], colB[4];
    #pragma unroll
    for (int i = 0; i < 4; ++i) { int r = m0 + i * 16 + l15; rowA[i] = r < M ? r : M - 1; }
    #pragma unroll
    for (int j = 0; j < 4; ++j) colB[j] = col0 + wc * 64 + j * 16 + l15;

    float bj[4];
    #pragma unroll
    for (int j = 0; j < 4; ++j) bj[j] = bias[colB[j]];

    f4v acc[4][4];
    #pragma unroll
    for (int i = 0; i < 4; ++i)
        #pragma unroll
        for (int j = 0; j < 4; ++j) acc[i][j] = (f4v){0.f, 0.f, 0.f, 0.f};

    for (int k0 = 0; k0 < K; k0 += 32) {
        s8v ah[4], al[4], bh[4], blv[4];
        #pragma unroll
        for (int i = 0; i < 4; ++i) {
            size_t off = (size_t)rowA[i] * K + k0 + koff;
            ah[i] = *(const s8v*)&Ahi[off];
            al[i] = *(const s8v*)&Alo[off];
        }
        #pragma unroll
        for (int j = 0; j < 4; ++j) {
            size_t off = (size_t)colB[j] * K + k0 + koff;
            bh[j]  = *(const s8v*)&Whi[off];
            blv[j] = *(const s8v*)&Wlo[off];
        }
        #pragma unroll
        for (int i = 0; i < 4; ++i)
            #pragma unroll
            for (int j = 0; j < 4; ++j) {
                acc[i][j] = __builtin_amdgcn_mfma_f32_16x16x32_bf16(ah[i], bh[j],  acc[i][j], 0, 0, 0);
                acc[i][j] = __builtin_amdgcn_mfma_f32_16x16x32_bf16(ah[i], blv[j], acc[i][j], 0, 0, 0);
                acc[i][j] = __builtin_amdgcn_mfma_f32_16x16x32_bf16(al[i], bh[j],  acc[i][j], 0, 0, 0);
            }
    }

    // stage as bf16 (+bias)
    #pragma unroll
    for (int i = 0; i < 4; ++i)
        #pragma unroll
        for (int r = 0; r < 4; ++r) {
            int lr = wr * 64 + i * 16 + lg * 4 + r;
            #pragma unroll
            for (int j = 0; j < 4; ++j)
                cst[lr][wc * 64 + j * 16 + l15] = bf16_rne(acc[i][j][r] + bj[j]);
        }
    __syncthreads();

    // coalesced 16B bf16 store
    {
        const int c8  = (t & 15) * 8;
        const int r16 = t >> 4;
        #pragma unroll
        for (int it = 0; it < 8; ++it) {
            int lr = it * 16 + r16;
            int row = blockIdx.x * 128 + lr;
            if (row >= M) continue;
            u16x8 v = *(const u16x8*)&cst[lr][c8];
            *(u16x8*)&C[(size_t)row * HCH + col0 + c8] = v;
        }
    }

    // att-dot per row (this head), from the bf16-rounded values
    {
        const int r2  = t >> 1;            // row 0..127
        const int ch0 = (t & 1) * 64;
        float q = 0.0f;
        #pragma unroll
        for (int c = 0; c < 64; c += 8) {
            u16x8 cv = *(const u16x8*)&cst[r2][ch0 + c];
            f4v a0 = *(const f4v*)&att[hh * 128 + ch0 + c];
            f4v a1 = *(const f4v*)&att[hh * 128 + ch0 + c + 4];
            q = fmaf(a0[0], bf16_to_f(cv[0]), q);
            q = fmaf(a0[1], bf16_to_f(cv[1]), q);
            q = fmaf(a0[2], bf16_to_f(cv[2]), q);
            q = fmaf(a0[3], bf16_to_f(cv[3]), q);
            q = fmaf(a1[0], bf16_to_f(cv[4]), q);
            q = fmaf(a1[1], bf16_to_f(cv[5]), q);
            q = fmaf(a1[2], bf16_to_f(cv[6]), q);
            q = fmaf(a1[3], bf16_to_f(cv[7]), q);
        }
        q += __shfl_xor(q, 1, 64);
        int row = blockIdx.x * 128 + r2;
        if ((t & 1) == 0 && row < M) D[row * 8 + hh] = q;
    }
}

// ---- final GEMM + ELU + fused pooling: 64-row tile, 2 waves ----
__global__ __launch_bounds__(128) void mfma_gemm2(
    const unsigned short* __restrict__ A1h,
    const unsigned short* __restrict__ B1hi, const unsigned short* __restrict__ B1lo, int K1,
    const unsigned short* __restrict__ A2hi, const unsigned short* __restrict__ A2lo,
    const unsigned short* __restrict__ B2hi, const unsigned short* __restrict__ B2lo, int K2,
    const float* __restrict__ bias, const int* __restrict__ batch,
    float* __restrict__ pooled, int M)
{
    __shared__ float cst[64][130];
    __shared__ int batch_s[64];
    const int t    = threadIdx.x;
    const int wc   = t >> 6, lane = t & 63;
    const int l15 = lane & 15, lg = lane >> 4;
    const int m0 = blockIdx.x * 64;
    const int n0 = wc * 64;
    const int koff = lg * 8;

    if (t < 64) {
        int row = m0 + t;
        batch_s[t] = (row < M) ? batch[row] : -1;
    }

    int rowA[4], colB[4];
    #pragma unroll
    for (int i = 0; i < 4; ++i) { int r = m0 + i * 16 + l15; rowA[i] = r < M ? r : M - 1; }
    #pragma unroll
    for (int j = 0; j < 4; ++j) colB[j] = n0 + j * 16 + l15;

    float bj[4];
    #pragma unroll
    for (int j = 0; j < 4; ++j) bj[j] = bias[colB[j]];

    f4v acc[4][4];
    #pragma unroll
    for (int i = 0; i < 4; ++i)
        #pragma unroll
        for (int j = 0; j < 4; ++j) acc[i][j] = (f4v){0.f, 0.f, 0.f, 0.f};

    for (int k0 = 0; k0 < K1; k0 += 32) {
        s8v ah[4], bh[4], blv[4];
        #pragma unroll
        for (int i = 0; i < 4; ++i)
            ah[i] = *(const s8v*)&A1h[(size_t)rowA[i] * K1 + k0 + koff];
        #pragma unroll
        for (int j = 0; j < 4; ++j) {
            size_t off = (size_t)colB[j] * K1 + k0 + koff;
            bh[j]  = *(const s8v*)&B1hi[off];
            blv[j] = *(const s8v*)&B1lo[off];
        }
        #pragma unroll
        for (int i = 0; i < 4; ++i)
            #pragma unroll
            for (int j = 0; j < 4; ++j) {
                acc[i][j] = __builtin_amdgcn_mfma_f32_16x16x32_bf16(ah[i], bh[j],  acc[i][j], 0, 0, 0);
                acc[i][j] = __builtin_amdgcn_mfma_f32_16x16x32_bf16(ah[i], blv[j], acc[i][j], 0, 0, 0);
            }
    }
    for (int k0 = 0; k0 < K2; k0 += 32) {
        s8v ah[4], al[4], bh[4], blv[4];
        #pragma unroll
        for (int i = 0; i < 4; ++i) {
            size_t off = (size_t)rowA[i] * K2 + k0 + koff;
            ah[i] = *(const s8v*)&A2hi[off];
            al[i] = *(const s8v*)&A2lo[off];
        }
        #pragma unroll
        for (int j = 0; j < 4; ++j) {
            size_t off = (size_t)colB[j] * K2 + k0 + koff;
            bh[j]  = *(const s8v*)&B2hi[off];
            blv[j] = *(const s8v*)&B2lo[off];
        }
        #pragma unroll
        for (int i = 0; i < 4; ++i)
            #pragma unroll
            for (int j = 0; j < 4; ++j) {
                acc[i][j] = __builtin_amdgcn_mfma_f32_16x16x32_bf16(ah[i], bh[j],  acc[i][j], 0, 0, 0);
                acc[i][j] = __builtin_amdgcn_mfma_f32_16x16x32_bf16(ah[i], blv[j], acc[i][j], 0, 0, 0);
                acc[i][j] = __builtin_amdgcn_mfma_f32_16x16x32_bf16(al[i], bh[j],  acc[i][j], 0, 0, 0);
            }
    }

    #pragma unroll
    for (int i = 0; i < 4; ++i)
        #pragma unroll
        for (int r = 0; r < 4; ++r) {
            int lr = i * 16 + lg * 4 + r;
            #pragma unroll
            for (int j = 0; j < 4; ++j) {
                float v = acc[i][j][r] + bj[j];
                v = v > 0.0f ? v : expm1f(v);   // ELU
                cst[lr][n0 + j * 16 + l15] = v;
            }
        }
    __syncthreads();

    const int col = t;
    float run = 0.0f;
    int cur_g = -2;
    #pragma unroll 4
    for (int r = 0; r < 64; ++r) {
        int g = batch_s[r];
        if (g != cur_g) {
            if (cur_g >= 0) atomicAdd(&pooled[cur_g * CPH + col], run);
            run = 0.0f; cur_g = g;
        }
        if (g >= 0) run += cst[r][col];
    }
    if (cur_g >= 0) atomicAdd(&pooled[cur_g * CPH + col], run);
}

// ---- CSR build: single-block scan, 4 elems/thread ----
__global__ __launch_bounds__(256) void scan_kernel(
    const int* __restrict__ deg, int* __restrict__ rowptr, int* __restrict__ wof)
{
    __shared__ int wsum[4];
    __shared__ int carry_s;
    const int t = threadIdx.x, wave = t >> 6, lane = t & 63;
    if (t == 0) { carry_s = 0; rowptr[0] = 0; }
    __syncthreads();
    for (int base = 0; base < N_NODES; base += 1024) {
        int idx = base + t * 4;
        int d[4], p[4];
        #pragma unroll
        for (int k = 0; k < 4; ++k)
            d[k] = (idx + k < N_NODES) ? deg[idx + k] : 0;
        p[0] = d[0]; p[1] = p[0] + d[1]; p[2] = p[1] + d[2]; p[3] = p[2] + d[3];
        int v = p[3];
        #pragma unroll
        for (int off = 1; off < 64; off <<= 1) {
            int u = __shfl_up(v, off, 64);
            if (lane >= off) v += u;
        }
        if (lane == 63) wsum[wave] = v;
        __syncthreads();
        int woff = carry_s;
        #pragma unroll
        for (int w = 0; w < 4; ++w) if (w < wave) woff += wsum[w];
        int tbase = woff + v - p[3];
        #pragma unroll
        for (int k = 0; k < 4; ++k) {
            if (idx + k < N_NODES) {
                rowptr[idx + k + 1] = tbase + p[k];
                wof[idx + k] = tbase + p[k] - d[k];
            }
        }
        __syncthreads();
        if (t == 255) carry_s = woff + v;
        __syncthreads();
    }
}

// ---- CSR build: scatter edge src ids ----
__global__ void scatter_kernel(const int* __restrict__ ei, int* __restrict__ wof,
                               int* __restrict__ csr_src)
{
    for (int e = blockIdx.x * blockDim.x + threadIdx.x; e < ETOT;
         e += gridDim.x * blockDim.x) {
        int src, dst;
        if (e < N_EDGES) { src = ei[e]; dst = ei[N_EDGES + e]; }
        else             { src = dst = e - N_EDGES; }
        int p = atomicAdd(&wof[dst], 1);
        csr_src[p] = src;
    }
}

// ---- fused logits + online softmax + aggregation, 8 ch/thread ----
// leaky(y) = 0.6y + 0.4|y|  =>  logit = 0.6(dl[src]+dr[dst]) + sum(0.4*att*|y|)
__global__ __launch_bounds__(128) void agg_fused(
    const unsigned short* __restrict__ xl_h, const unsigned short* __restrict__ xr_h,
    const float* __restrict__ att,
    const float* __restrict__ dl, const float* __restrict__ dr,
    const int* __restrict__ rowptr, const int* __restrict__ csr_src,
    unsigned short* __restrict__ agg_h)
{
    const int dst = blockIdx.x;
    const int t = threadIdx.x;       // 0..127
    const int h = t >> 4;            // head, 16 lanes each
    const int beg = rowptr[dst], end = rowptr[dst + 1];

    const u16x8 bh8 = *(const u16x8*)&xr_h[(size_t)dst * HCH + t * 8];
    f8v b;
    #pragma unroll
    for (int e = 0; e < 8; ++e) b[e] = bf16_to_f(bh8[e]);
    f8v w04;
    {
        f4v a0 = *(const f4v*)&att[t * 8];
        f4v a1 = *(const f4v*)&att[t * 8 + 4];
        #pragma unroll
        for (int e = 0; e < 4; ++e) { w04[e] = 0.4f * a0[e]; w04[e + 4] = 0.4f * a1[e]; }
    }
    const float pb = 0.6f * dr[dst * 8 + h];

    float m = -__builtin_inff(), s = 0.0f;
    f8v acc = {0.f, 0.f, 0.f, 0.f, 0.f, 0.f, 0.f, 0.f};

    int j = beg;
    for (; j + 1 < end; j += 2) {
        const int s0 = csr_src[j], s1 = csr_src[j + 1];
        const u16x8 vh0 = *(const u16x8*)&xl_h[(size_t)s0 * HCH + t * 8];
        const u16x8 vh1 = *(const u16x8*)&xl_h[(size_t)s1 * HCH + t * 8];
        const float d0 = dl[s0 * 8 + h], d1 = dl[s1 * 8 + h];
        f8v v0, v1;
        #pragma unroll
        for (int e = 0; e < 8; ++e) { v0[e] = bf16_to_f(vh0[e]); v1[e] = bf16_to_f(vh1[e]); }

        float q0 = w04[0] * __builtin_fabsf(v0[0] + b[0]);
        float q1 = w04[0] * __builtin_fabsf(v1[0] + b[0]);
        #pragma unroll
        for (int e = 1; e < 8; ++e) {
            q0 = fmaf(w04[e], __builtin_fabsf(v0[e] + b[e]), q0);
            q1 = fmaf(w04[e], __builtin_fabsf(v1[e] + b[e]), q1);
        }
        #pragma unroll
        for (int off = 8; off; off >>= 1) {
            q0 += __shfl_xor(q0, off, 16);
            q1 += __shfl_xor(q1, off, 16);
        }
        const float p0 = fmaf(0.6f, d0, q0) + pb;
        const float p1 = fmaf(0.6f, d1, q1) + pb;

        const float mx = fmaxf(p0, p1);
        if (mx > m) {
            float scale = __expf(m - mx);   // first pair: exp(-inf)=0
            float e0 = __expf(p0 - mx), e1 = __expf(p1 - mx);
            s = s * scale + e0 + e1;
            acc = acc * scale + v0 * e0 + v1 * e1;
            m = mx;
        } else {
            float e0 = __expf(p0 - m), e1 = __expf(p1 - m);
            s += e0 + e1;
            acc += v0 * e0 + v1 * e1;
        }
    }
    if (j < end) {   // tail edge
        const int s0 = csr_src[j];
        const u16x8 vh0 = *(const u16x8*)&xl_h[(size_t)s0 * HCH + t * 8];
        const float d0 = dl[s0 * 8 + h];
        f8v v0;
        #pragma unroll
        for (int e = 0; e < 8; ++e) v0[e] = bf16_to_f(vh0[e]);
        float q0 = w04[0] * __builtin_fabsf(v0[0] + b[0]);
        #pragma unroll
        for (int e = 1; e < 8; ++e)
            q0 = fmaf(w04[e], __builtin_fabsf(v0[e] + b[e]), q0);
        #pragma unroll
        for (int off = 8; off; off >>= 1) q0 += __shfl_xor(q0, off, 16);
        const float p0 = fmaf(0.6f, d0, q0) + pb;
        if (p0 > m) {
            float scale = __expf(m - p0);
            s = s * scale + 1.0f;
            acc = acc * scale + v0;
            m = p0;
        } else {
            float e0 = __expf(p0 - m);
            s += e0;
            acc += v0 * e0;
        }
    }

    const float inv = 1.0f / (s + 1e-16f);
    f8v r = acc * inv;
    u16x8 hv;
    #pragma unroll
    for (int e = 0; e < 8; ++e) hv[e] = bf16_rne(r[e]);
    *(u16x8*)&agg_h[(size_t)dst * HCH + t * 8] = hv;
}

// ---- MLP head: one thread per graph (counts via binary search on batch) ----
__global__ __launch_bounds__(64) void head_kernel(
    const float* __restrict__ pooled, const int* __restrict__ batch,
    const float* __restrict__ W1, const float* __restrict__ b1,
    const float* __restrict__ W2, const float* __restrict__ b2,
    const float* __restrict__ W3, const float* __restrict__ b3,
    float* __restrict__ out)
{
    const int g = threadIdx.x;
    int lo = 0, hi = N_NODES;
    while (lo < hi) { int mid = (lo + hi) >> 1; if (batch[mid] <  g) lo = mid + 1; else hi = mid; }
    const int s0 = lo;
    hi = N_NODES;
    while (lo < hi) { int mid = (lo + hi) >> 1; if (batch[mid] <= g) lo = mid + 1; else hi = mid; }
    const float inv = 1.0f / fmaxf((float)(lo - s0), 1.0f);

    float y1[16];
    for (int j = 0; j < 16; ++j) {
        float s = b1[j];
        for (int k = 0; k < CPH; ++k) s += W1[j * CPH + k] * (pooled[g * CPH + k] * inv);
        y1[j] = fmaxf(s, 0.0f);
    }
    float y2[32];
    for (int j = 0; j < 32; ++j) {
        float s = b2[j];
        for (int k = 0; k < 16; ++k) s += W2[j * 16 + k] * y1[k];
        y2[j] = fmaxf(s, 0.0f);
    }
    for (int u = 0; u < 5; ++u) {
        float s = b3[u];
        for (int k = 0; k < 32; ++k) s += W3[u * 32 + k] * y2[k];
        out[g * 5 + u] = s;
    }
}

extern "C" void kernel_launch(void* const* d_in, const int* in_sizes, int n_in,
                              void* d_out, int out_size, void* d_ws, size_t ws_size,
                              hipStream_t stream)
{
    const float* x         = (const float*)d_in[0];
    const int*   ei        = (const int*)  d_in[1];
    const int*   batch     = (const int*)  d_in[2];
    const float* Wl        = (const float*)d_in[3];
    const float* bl        = (const float*)d_in[4];
    const float* Wr        = (const float*)d_in[5];
    const float* br        = (const float*)d_in[6];
    const float* att       = (const float*)d_in[7];
    const float* Wres      = (const float*)d_in[8];
    const float* bias_conv = (const float*)d_in[9];
    const float* Wlin      = (const float*)d_in[10];
    const float* blin      = (const float*)d_in[11];
    const float* W1        = (const float*)d_in[12];
    const float* b1        = (const float*)d_in[13];
    const float* W2        = (const float*)d_in[14];
    const float* b2        = (const float*)d_in[15];
    const float* W3        = (const float*)d_in[16];
    const float* b3        = (const float*)d_in[17];
    float* out = (float*)d_out;

    // ---- workspace layout (~139 MB) ----
    unsigned short* xl_h  = (unsigned short*)d_ws;              // N*HCH u16 41 MB
    unsigned short* xr_h  = xl_h + (size_t)N_NODES * HCH;       // N*HCH u16 41 MB
    unsigned short* agg_h = xr_h + (size_t)N_NODES * HCH;       // N*HCH u16 41 MB
    float* pooled = (float*)(agg_h + (size_t)N_NODES * HCH);    // NG*CPH f
    float* bcomb  = pooled + NG * CPH;                          // 128 f
    float* dl     = bcomb + 128;                                // N*8 f
    float* dr     = dl + (size_t)N_NODES * 8;                   // N*8 f
    unsigned short* x_hi  = (unsigned short*)(dr + (size_t)N_NODES * 8);
    unsigned short* x_lo  = x_hi  + (size_t)N_NODES * IN_CH;
    unsigned short* wl_hi = x_lo  + (size_t)N_NODES * IN_CH;
    unsigned short* wl_lo = wl_hi + HCH * IN_CH;
    unsigned short* wr_hi = wl_lo + HCH * IN_CH;
    unsigned short* wr_lo = wr_hi + HCH * IN_CH;
    unsigned short* wn_hi = wr_lo + HCH * IN_CH;
    unsigned short* wn_lo = wn_hi + CPH * HCH;
    unsigned short* wc_hi = wn_lo + CPH * HCH;
    unsigned short* wc_lo = wc_hi + CPH * IN_CH;
    int* deg     = (int*)(wc_lo + CPH * IN_CH);                 // N
    int* rowptr  = deg + N_NODES;                               // N+1
    int* wof     = rowptr + N_NODES + 1;                        // N
    int* csr_src = wof + N_NODES;                               // ETOT

    init_kernel<<<(N_NODES + 255) / 256, 256, 0, stream>>>(deg, pooled);

    cvt_all<<<NCVT + 128, 256, 0, stream>>>(x, Wl, Wr, Wlin,
                                            x_hi, x_lo, wl_hi, wl_lo,
                                            wr_hi, wr_lo, wn_hi, wn_lo,
                                            ei, deg,
                                            Wres, bias_conv, blin,
                                            wc_hi, wc_lo, bcomb);

    dim3 gp((N_NODES + 127) / 128, 16);
    proj_gemm<<<gp, 256, 0, stream>>>(x_hi, x_lo, wl_hi, wl_lo, wr_hi, wr_lo,
                                      bl, br, att, xl_h, xr_h, dl, dr, N_NODES);

    scan_kernel<<<1, 256, 0, stream>>>(deg, rowptr, wof);
    scatter_kernel<<<1024, 256, 0, stream>>>(ei, wof, csr_src);

    agg_fused<<<N_NODES, 128, 0, stream>>>(xl_h, xr_h, att, dl, dr,
                                           rowptr, csr_src, agg_h);

    dim3 g2((N_NODES + 63) / 64, 1);
    mfma_gemm2<<<g2, 128, 0, stream>>>(agg_h, wn_hi, wn_lo, HCH,
                                       x_hi, x_lo, wc_hi, wc_lo, IN_CH,
                                       bcomb, batch, pooled, N_NODES);

    head_kernel<<<1, 64, 0, stream>>>(pooled, batch, W1, b1, W2, b2, W3, b3, out);
}